// Round 17
// baseline (5308.122 us; speedup 1.0000x reference)
//
#include <hip/hip_runtime.h>

// ---------------------------------------------------------------------------
// Fused recurrent multimodal net. T=128, N=2048. 128 blocks x 16 rows.
// Round 16: r15 base + on-chip weight caching. Model now closed: step time ==
// weight-bytes/block / ~13 B/cy/CU (per-block ingest invariant). So: cut bytes.
// (1) P1 gate tiles persist in VGPRs across all 128 steps (48 regs/wave,
//     loaded once) -> P1 has zero global loads. (2) 48KB LDS weight cache for
//     att1-l1 tiles (6 of 14 per n) -> P3 rings only 8. 902 -> 686 KB/step.
// ---------------------------------------------------------------------------

#define T_STEPS 128

typedef __attribute__((ext_vector_type(8))) short bf16x8;
typedef __attribute__((ext_vector_type(4))) float f32x4;
typedef __attribute__((ext_vector_type(2))) unsigned long long ull2;

#define MFMA_B16(a,b,c) __builtin_amdgcn_mfma_f32_16x16x32_bf16((a),(b),(c),0,0,0)

__device__ __forceinline__ unsigned short f2b(float v) {
  union { float f; unsigned u; } x; x.f = v;
  unsigned r = x.u + 0x7fffu + ((x.u >> 16) & 1u);
  return (unsigned short)(r >> 16);
}
__device__ __forceinline__ float b2f(unsigned short u) {
  union { unsigned u; float f; } x; x.u = ((unsigned)u) << 16; return x.f;
}
__device__ __forceinline__ float sigm(float x){ return 1.0f/(1.0f + __expf(-x)); }
__device__ __forceinline__ float tanh_(float x){ return 1.0f - 2.0f/(1.0f + __expf(2.0f*x)); }

// ---- core LDS layout ----
#define OFF_XL     0
#define OFF_XA     10496
#define OFF_XI     13824
#define OFF_CSTAR  16128
#define OFF_ATT    30720
#define OFF_HID    45312
#define OFF_G1H    53760
#define OFF_G2H    56064
#define OFF_FEATS  58368
#define OFF_BIAS   69888
#define OFF_XP     79368    // 16 x 968 bf16 (30976 B)
#define OFF_WC     110344   // 48 tiles x 1KB weight cache
#define LDS_BYTES  159496   // <= 160KiB; 1 block/CU

// ---- bias layout ----
#define BG_LIN 0
#define BG_AC  384
#define BG_IM  576
#define B_A1H  960
#define B_LOG  1088
#define B_A2H  1536
#define B_CHAT 1792
#define B_G1H  1920
#define B_G2H  1984
#define B_GM1  2048
#define B_GM2  2176
#define B_OUTH 2304
#define B_OUT2 2368
#define N_BIAS 2369

#define N_TILES 1718
#define PACK_BYTES ((size_t)N_TILES * 1024)
#define XP_ELEMS ((size_t)262144 * 960)
#define XP_BYTES (XP_ELEMS * 2)

#define LA(off,st,row,kk)  (*(const bf16x8*)(lds + (off) + ((((row)*(st)) + (kk)) << 1)))
#define LB(tile)           (*(const bf16x8*)(packc + (((size_t)(tile)) << 10) + (lane << 4)))
#define STB(off,st,row,col,v) (*(unsigned short*)(lds + (off) + ((((row)*(st)) + (col)) << 1)) = f2b(v))
#define LDB(off,st,row,col)   b2f(*(const unsigned short*)(lds + (off) + ((((row)*(st)) + (col)) << 1)))

struct PP { const float* p[35]; };

// ---------------------------------------------------------------------------
// Register async-pipeline primitives (depth-8, issue-1/consume-1; r8/r12)
// ---------------------------------------------------------------------------
__device__ __forceinline__ void vmw(int n) {
  switch (n) {
    case 0: asm volatile("s_waitcnt vmcnt(0)"); break;
    case 1: asm volatile("s_waitcnt vmcnt(1)"); break;
    case 2: asm volatile("s_waitcnt vmcnt(2)"); break;
    case 3: asm volatile("s_waitcnt vmcnt(3)"); break;
    case 4: asm volatile("s_waitcnt vmcnt(4)"); break;
    case 5: asm volatile("s_waitcnt vmcnt(5)"); break;
    case 6: asm volatile("s_waitcnt vmcnt(6)"); break;
    default: asm volatile("s_waitcnt vmcnt(7)"); break;
  }
  __builtin_amdgcn_sched_barrier(0);
}

#define ISSUE_B(dst, tile)                                                   \
  { unsigned off_ = (((unsigned)(tile)) << 10) + ((unsigned)lane << 4);      \
    asm volatile("global_load_dwordx4 %0, %1, %2"                            \
                 : "=v"(dst) : "v"(off_), "s"(packc)); }

template<int NTT, class FT, class FB>
__device__ __forceinline__ void reg_loop(const char* packc, int lane,
                                         FT&& tile_of, FB&& body)
{
  constexpr int D = (NTT < 8) ? NTT : 8;
  bf16x8 b[8];
  #pragma unroll
  for (int i = 0; i < D; ++i) ISSUE_B(b[i], tile_of(i));
  #pragma unroll
  for (int i = 0; i < NTT; ++i) {
    vmw((NTT-1-i) < 7 ? (NTT-1-i) : 7);
    body(i, b[i & 7]);
    __builtin_amdgcn_sched_barrier(0);
    if (i + 8 < NTT) ISSUE_B(b[i & 7], tile_of(i + 8));
  }
}

// ---------------------------------------------------------------------------
// Pack kernel (r12/r15, unchanged)
// ---------------------------------------------------------------------------
__device__ __forceinline__ float gate_src(const float* Wih, const float* Whh,
                                          int H, int din, int nksx, int col, int k)
{
  int blk = col >> 6, gate = (col >> 4) & 3, u = col & 15;
  int unit = blk*16 + u;
  if (unit >= H) return 0.f;
  int row = gate*H + unit;
  int xk = nksx*32;
  if (k < xk) return (k < din) ? Wih[row*din + k] : 0.f;
  int kk = k - xk;
  return (kk < H) ? Whh[row*H + kk] : 0.f;
}
__device__ __forceinline__ float gate_h(const float* Whh, int H, int col, int k)
{
  int blk = col >> 6, gate = (col >> 4) & 3, u = col & 15;
  int unit = blk*16 + u;
  if (unit >= H || k >= H) return 0.f;
  return Whh[(gate*H + unit)*H + k];
}
__device__ __forceinline__ float gate_x(const float* Wih, int H, int din, int col, int k)
{
  int blk = col >> 6, gate = (col >> 4) & 3, u = col & 15;
  int unit = blk*16 + u;
  if (unit >= H || k >= din) return 0.f;
  return Wih[(gate*H + unit)*din + k];
}
__device__ __forceinline__ float plain_src(const float* W, int nout, int kdim, int col, int k)
{
  return (col < nout && k < kdim) ? W[col*kdim + k] : 0.f;
}

__global__ __launch_bounds__(256) void pack_kernel(PP P, unsigned short* __restrict__ pack,
                                                   float* __restrict__ bias)
{
  int tid = blockIdx.x*blockDim.x + threadIdx.x;
  int wv = tid >> 6, lane = tid & 63;
  int nw = (gridDim.x*blockDim.x) >> 6;
  int c = lane & 15, kg = lane >> 4;

  for (int tile = wv; tile < N_TILES; tile += nw) {
    unsigned short* dst = pack + ((size_t)tile << 9) + lane*8;
    #pragma unroll
    for (int i = 0; i < 8; ++i) {
      int r = tile; int nt, ks; float v; int kk;
      if (r < 312)       { nt=r/13; ks=r-nt*13; kk=ks*32+kg*8+i; v = gate_src(P.p[3], P.p[4], 88,300,10, nt*16+c, kk); }
      else if (r < 372)  { r-=312; nt=r/5;  ks=r-nt*5;  kk=ks*32+kg*8+i; v = gate_src(P.p[7], P.p[8], 48, 74, 3, nt*16+c, kk); }
      else if (r < 492)  { r-=372; nt=r/5;  ks=r-nt*5;  kk=ks*32+kg*8+i; v = gate_src(P.p[11],P.p[12],88, 35, 2, nt*16+c, kk); }
      else if (r < 604)  { r-=492; nt=r/14; ks=r-nt*14; kk=ks*32+kg*8+i; v = plain_src(P.p[15],128,448, nt*16+c, kk); }
      else if (r < 716)  { r-=604; nt=r/4;  ks=r-nt*4;  kk=ks*32+kg*8+i; v = plain_src(P.p[17],448,128, nt*16+c, kk); }
      else if (r < 940)  { r-=716; nt=r/14; ks=r-nt*14; kk=ks*32+kg*8+i; v = plain_src(P.p[19],256,448, nt*16+c, kk); }
      else if (r < 1004) { r-=940; nt=r/8;  ks=r-nt*8;  kk=ks*32+kg*8+i; v = plain_src(P.p[21],128,256, nt*16+c, kk); }
      else if (r < 1076) { r-=1004; nt=r/18; ks=r-nt*18; kk=ks*32+kg*8+i; v = plain_src(P.p[23], 64,576, nt*16+c, kk); }
      else if (r < 1148) { r-=1076; nt=r/18; ks=r-nt*18; kk=ks*32+kg*8+i; v = plain_src(P.p[27], 64,576, nt*16+c, kk); }
      else if (r < 1164) { r-=1148; nt=r/2;  ks=r-nt*2;  kk=ks*32+kg*8+i; v = plain_src(P.p[25],128, 64, nt*16+c, kk); }
      else if (r < 1180) { r-=1164; nt=r/2;  ks=r-nt*2;  kk=ks*32+kg*8+i; v = plain_src(P.p[29],128, 64, nt*16+c, kk); }
      else if (r < 1224) { r-=1180; nt=r/11; ks=r-nt*11; kk=ks*32+kg*8+i; v = plain_src(P.p[31], 64,352, nt*16+c, kk); }
      else if (r < 1226) { r-=1224; ks=r;    kk=ks*32+kg*8+i; v = plain_src(P.p[33],  1, 64, c, kk); }
      else if (r < 1298) { r-=1226; nt=r/3;  ks=r-nt*3;  kk=ks*32+kg*8+i; v = gate_h(P.p[4], 88, nt*16+c, kk); }
      else if (r < 1322) { r-=1298; nt=r/2;  ks=r-nt*2;  kk=ks*32+kg*8+i; v = gate_h(P.p[8], 48, nt*16+c, kk); }
      else if (r < 1394) { r-=1322; nt=r/3;  ks=r-nt*3;  kk=ks*32+kg*8+i; v = gate_h(P.p[12],88, nt*16+c, kk); }
      else if (r < 1634) { r-=1394; nt=r/10; ks=r-nt*10; kk=ks*32+kg*8+i; v = gate_x(P.p[3], 88,300, nt*16+c, kk); }
      else if (r < 1670) { r-=1634; nt=r/3;  ks=r-nt*3;  kk=ks*32+kg*8+i; v = gate_x(P.p[7], 48, 74, nt*16+c, kk); }
      else               { r-=1670; nt=r/2;  ks=r-nt*2;  kk=ks*32+kg*8+i; v = gate_x(P.p[11],88, 35, nt*16+c, kk); }
      dst[i] = f2b(v);
    }
  }

  int NT = gridDim.x*blockDim.x;
  for (int b = tid; b < N_BIAS; b += NT) {
    float v; int r = b;
    if (r < 384)       { int blk=r>>6, g=(r>>4)&3, u=r&15, un=blk*16+u; v = (un<88) ? P.p[5][g*88+un] + P.p[6][g*88+un]  : 0.f; }
    else if (r < 576)  { r-=384; int blk=r>>6, g=(r>>4)&3, u=r&15, un=blk*16+u; v = (un<48) ? P.p[9][g*48+un] + P.p[10][g*48+un] : 0.f; }
    else if (r < 960)  { r-=576; int blk=r>>6, g=(r>>4)&3, u=r&15, un=blk*16+u; v = (un<88) ? P.p[13][g*88+un]+ P.p[14][g*88+un] : 0.f; }
    else if (r < 1088) v = P.p[16][r-960];
    else if (r < 1536) v = P.p[18][r-1088];
    else if (r < 1792) v = P.p[20][r-1536];
    else if (r < 1920) v = P.p[22][r-1792];
    else if (r < 1984) v = P.p[24][r-1920];
    else if (r < 2048) v = P.p[28][r-1984];
    else if (r < 2176) v = P.p[26][r-2048];
    else if (r < 2304) v = P.p[30][r-2176];
    else if (r < 2368) v = P.p[32][r-2304];
    else               v = P.p[34][0];
    bias[b] = v;
  }
}

// ---------------------------------------------------------------------------
// XP pre-pass (r12, unchanged)
// ---------------------------------------------------------------------------
__global__ __launch_bounds__(1024) void xproj_kernel(
    const float* __restrict__ xlin, const float* __restrict__ xac,
    const float* __restrict__ xim, const unsigned short* __restrict__ pack,
    unsigned short* __restrict__ xp)
{
  __shared__ alignas(16) char slds[81920];
  const char* packc = (const char*)pack;
  const int tid = threadIdx.x, lane = tid & 63, w = tid >> 6;
  const int rA = lane & 15, gA = lane >> 4;
  const int mt = w & 7, half = w >> 3;
  const size_t m0 = (size_t)blockIdx.x * 128;
  const int mr = mt * 16;

  for (int p = tid; p < 9600; p += 1024) {
    int row = p/75, d = p - row*75;
    float4 v = *(const float4*)(xlin + (m0+row)*300 + d*4);
    unsigned long long u = (unsigned long long)f2b(v.x)
      | ((unsigned long long)f2b(v.y) << 16)
      | ((unsigned long long)f2b(v.z) << 32)
      | ((unsigned long long)f2b(v.w) << 48);
    *(unsigned long long*)(slds + (((size_t)row*320 + d*4) << 1)) = u;
  }
  for (int p = tid; p < 1280; p += 1024) {
    int row = p/10, cc = 300 + 2*(p - row*10);
    *(unsigned*)(slds + (((size_t)row*320 + cc) << 1)) = 0;
  }
  __syncthreads();
  for (int blk = half*3; blk < half*3 + 3; ++blk) {
    #pragma unroll
    for (int q = 0; q < 4; ++q) {
      f32x4 acc = {0.f,0.f,0.f,0.f};
      int nt = blk*4 + q;
      bf16x8 a = *(const bf16x8*)(slds + ((((mr+rA)*320) + gA*8) << 1));
      reg_loop<10>(packc, lane,
        [&](int i){ return 1394 + nt*10 + i; },
        [&](int i, bf16x8 bv){
          acc = MFMA_B16(a, bv, acc);
          if (i + 1 < 10) a = *(const bf16x8*)(slds + ((((mr+rA)*320) + (i+1)*32 + gA*8) << 1));
        });
      #pragma unroll
      for (int j = 0; j < 4; ++j)
        xp[(m0 + mr + gA*4 + j)*960 + blk*64 + q*16 + rA] = f2b(acc[j]);
    }
  }
  __syncthreads();

  for (int p = tid; p < 4736; p += 1024) {
    int row = p/37, d = p - row*37;
    float2 v = *(const float2*)(xac + (m0+row)*74 + d*2);
    unsigned uu = (unsigned)f2b(v.x) | ((unsigned)f2b(v.y) << 16);
    *(unsigned*)(slds + (((size_t)row*96 + d*2) << 1)) = uu;
  }
  for (int p = tid; p < 1408; p += 1024) {
    int row = p/11, cc = 74 + 2*(p - row*11);
    *(unsigned*)(slds + (((size_t)row*96 + cc) << 1)) = 0;
  }
  __syncthreads();
  if (half == 0) {
    for (int blk = 0; blk < 3; ++blk) {
      #pragma unroll
      for (int q = 0; q < 4; ++q) {
        f32x4 acc = {0.f,0.f,0.f,0.f};
        int nt = blk*4 + q;
        bf16x8 a = *(const bf16x8*)(slds + ((((mr+rA)*96) + gA*8) << 1));
        reg_loop<3>(packc, lane,
          [&](int i){ return 1634 + nt*3 + i; },
          [&](int i, bf16x8 bv){
            acc = MFMA_B16(a, bv, acc);
            if (i + 1 < 3) a = *(const bf16x8*)(slds + ((((mr+rA)*96) + (i+1)*32 + gA*8) << 1));
          });
        #pragma unroll
        for (int j = 0; j < 4; ++j)
          xp[(m0 + mr + gA*4 + j)*960 + 384 + blk*64 + q*16 + rA] = f2b(acc[j]);
      }
    }
  }
  __syncthreads();

  for (int p = tid; p < 4480; p += 1024) {
    int row = p/35, d = p - row*35;
    *(unsigned short*)(slds + (((size_t)row*64 + d) << 1)) = f2b(xim[(m0+row)*35 + d]);
  }
  for (int p = tid; p < 3712; p += 1024) {
    int row = p/29, cc = 35 + (p - row*29);
    *(unsigned short*)(slds + (((size_t)row*64 + cc) << 1)) = 0;
  }
  __syncthreads();
  if (half == 1) {
    for (int blk = 0; blk < 6; ++blk) {
      #pragma unroll
      for (int q = 0; q < 4; ++q) {
        f32x4 acc = {0.f,0.f,0.f,0.f};
        int nt = blk*4 + q;
        bf16x8 a = *(const bf16x8*)(slds + ((((mr+rA)*64) + gA*8) << 1));
        reg_loop<2>(packc, lane,
          [&](int i){ return 1670 + nt*2 + i; },
          [&](int i, bf16x8 bv){
            acc = MFMA_B16(a, bv, acc);
            if (i + 1 < 2) a = *(const bf16x8*)(slds + ((((mr+rA)*64) + 32 + gA*8) << 1));
          });
        #pragma unroll
        for (int j = 0; j < 4; ++j)
          xp[(m0 + mr + gA*4 + j)*960 + 576 + blk*64 + q*16 + rA] = f2b(acc[j]);
      }
    }
  }
}

// ---------------------------------------------------------------------------
// Main fused kernel (r15 structure + persistent gate regs + LDS weight cache)
// ---------------------------------------------------------------------------
__device__ __forceinline__ void stage_xp(char* lds, const unsigned short* __restrict__ xp,
                                         int t, int n0, int tid0, int nthr)
{
  const size_t base = ((size_t)t*2048 + n0)*960;
  for (int q = tid0; q < 1920; q += nthr) {
    int row = q/120, ch = q - row*120;
    ull2 v = __builtin_nontemporal_load((const ull2*)(xp + base + (size_t)row*960 + ch*8));
    *(ull2*)(lds + OFF_XP + (((size_t)row*968 + ch*8) << 1)) = v;
  }
}

__global__ __launch_bounds__(1024) void fused_kernel(
    const unsigned short* __restrict__ pack, const float* __restrict__ biasg,
    const unsigned short* __restrict__ xp, float* __restrict__ out)
{
  __shared__ alignas(16) char lds[LDS_BYTES];
  const char* packc = (const char*)pack;
  const int tid  = threadIdx.x;
  const int lane = tid & 63;
  const int w    = tid >> 6;
  const int rA   = lane & 15;
  const int gA   = lane >> 4;
  const int n0   = blockIdx.x * 16;
  float* biasLds = (float*)(lds + OFF_BIAS);

  for (int i = tid; i < (OFF_BIAS >> 2); i += 1024) ((int*)lds)[i] = 0;
  __syncthreads();
  for (int i = tid; i < N_BIAS; i += 1024) biasLds[i] = biasg[i];
  stage_xp(lds, xp, 0, n0, tid, 1024);
  // ---- preload LDS weight cache: att1-l1 tiles (492 + n*14 + i), i<6 ----
  for (int idx = tid; idx < 48*64; idx += 1024) {
    int slot = idx >> 6, l = idx & 63;
    int nn = slot / 6, ii = slot - nn*6;
    int tile = 492 + nn*14 + ii;
    bf16x8 v = *(const bf16x8*)(packc + ((size_t)tile << 10) + (l << 4));
    *(bf16x8*)(lds + OFF_WC + ((size_t)slot << 10) + (l << 4)) = v;
  }
  __syncthreads();

  // ---- per-wave P1 parameters (hoisted) + persistent gate weights ----
  int blkP, tbP, nksP, hsecP, bbP, cbP, HP;
  if (w < 6)       { blkP=w;   tbP=1226+w*12;     nksP=3; hsecP=0;   bbP=BG_LIN; cbP=0   + w*64;      HP=88; }
  else if (w < 9)  { blkP=w-6; tbP=1298+(w-6)*8;  nksP=2; hsecP=88;  bbP=BG_AC;  cbP=384 + (w-6)*64;  HP=48; }
  else if (w < 15) { blkP=w-9; tbP=1322+(w-9)*12; nksP=3; hsecP=136; bbP=BG_IM;  cbP=576 + (w-9)*64;  HP=88; }
  else             { blkP=0;   tbP=1226;          nksP=3; hsecP=0;   bbP=BG_LIN; cbP=0;               HP=88; }

  bf16x8 gw[12];
  {
    int ntile = nksP*4;
    #pragma unroll
    for (int i = 0; i < 12; ++i) gw[i] = LB(tbP + (i < ntile ? i : 0));
  }
  bf16x8 ow0 = LB(1224), ow1 = LB(1225);

  float cst[4]  = {};
  float mreg[4] = {};

  for (int t = 0; t < T_STEPS; ++t) {
    // ---- Phase 1: gates from persistent regs (zero global loads); w15: out2
    f32x4 gacc[4];
    if (w == 15) {
      if (t > 0) {
        float bv = biasLds[B_OUT2];
        f32x4 oa0 = {bv,bv,bv,bv};
        oa0 = MFMA_B16(LA(OFF_HID,72, rA, gA*8),      ow0, oa0);
        oa0 = MFMA_B16(LA(OFF_HID,72, rA, 32 + gA*8), ow1, oa0);
        if (rA == 0) {
          #pragma unroll
          for (int j = 0; j < 4; ++j)
            __builtin_nontemporal_store(oa0[j], &out[(size_t)(n0 + gA*4 + j)*T_STEPS + (t-1)]);
        }
      }
    } else {
      #pragma unroll
      for (int q = 0; q < 4; ++q) {
        float bv = biasLds[bbP + blkP*64 + q*16 + rA];
        #pragma unroll
        for (int j = 0; j < 4; ++j) {
          int row = gA*4 + j;
          float xv = b2f(*(const unsigned short*)(lds + OFF_XP + (((size_t)row*968 + cbP + q*16 + rA) << 1)));
          gacc[q][j] = bv + xv;
        }
      }
      if (nksP == 3) {
        #pragma unroll
        for (int s = 0; s < 3; ++s) {
          bf16x8 a = LA(OFF_FEATS,360, rA, hsecP + s*32 + gA*8);
          #pragma unroll
          for (int q = 0; q < 4; ++q) gacc[q] = MFMA_B16(a, gw[q*3+s], gacc[q]);
        }
      } else {
        #pragma unroll
        for (int s = 0; s < 2; ++s) {
          bf16x8 a = LA(OFF_FEATS,360, rA, hsecP + s*32 + gA*8);
          #pragma unroll
          for (int q = 0; q < 4; ++q) gacc[q] = MFMA_B16(a, gw[q*2+s], gacc[q]);
        }
      }
    }
    __syncthreads();

    // ---- Phase 2: LSTM elementwise ----
    if (w < 15) {
      int unit = blkP*16 + rA;
      if (unit < HP) {
        #pragma unroll
        for (int j = 0; j < 4; ++j) {
          float iv = sigm (gacc[0][j]);
          float fv = sigm (gacc[1][j]);
          float gv = tanh_(gacc[2][j]);
          float ov = sigm (gacc[3][j]);
          float cp = cst[j];
          float cn = fv*cp + iv*gv;
          float hn = ov*tanh_(cn);
          cst[j] = cn;
          int row = gA*4 + j;
          STB(OFF_CSTAR,456, row, hsecP + unit,        cp);
          STB(OFF_CSTAR,456, row, 224 + hsecP + unit,  cn);
          STB(OFF_FEATS,360, row, hsecP + unit,        hn);
        }
      }
    }
    __syncthreads();

    // ---- Phase 3: att1 layer1 (6 tiles from LDS cache + 8 via ring) ----
    if (w < 8) {
      int n = w;
      float bv = biasLds[B_A1H + n*16 + rA];
      f32x4 a0v = {bv,bv,bv,bv};
      #pragma unroll
      for (int i = 0; i < 6; ++i) {
        bf16x8 bw = *(const bf16x8*)(lds + OFF_WC + ((size_t)(n*6 + i) << 10) + (lane << 4));
        bf16x8 a = LA(OFF_CSTAR,456, rA, i*32+gA*8);
        a0v = MFMA_B16(a, bw, a0v);
      }
      reg_loop<8>(packc, lane,
        [&](int i){ return 492 + n*14 + 6 + i; },
        [&](int i, bf16x8 bv8){
          bf16x8 a = LA(OFF_CSTAR,456, rA, (6+i)*32+gA*8);
          a0v = MFMA_B16(a, bv8, a0v);
        });
      #pragma unroll
      for (int j = 0; j < 4; ++j)
        STB(OFF_HID,136, gA*4 + j, n*16 + rA, fmaxf(a0v[j], 0.f));
    }
    __syncthreads();

    // ---- Phase 4: att1 layer2 -> logits ----
    {
      float bv1 = biasLds[B_LOG + w*16 + rA];
      if (w < 12) {
        float bv2 = biasLds[B_LOG + (w+16)*16 + rA];
        f32x4 l0 = {bv1,bv1,bv1,bv1}, l1 = {bv2,bv2,bv2,bv2};
        bf16x8 a = LA(OFF_HID,136, rA, gA*8);
        reg_loop<8>(packc, lane,
          [&](int i){ int tau = (i < 4) ? w : (w + 16); return 604 + tau*4 + (i & 3); },
          [&](int i, bf16x8 bv8){
            if (i < 4) l0 = MFMA_B16(a, bv8, l0); else l1 = MFMA_B16(a, bv8, l1);
            if (i + 1 < 8) a = LA(OFF_HID,136, rA, ((i+1)&3)*32+gA*8);
          });
        #pragma unroll
        for (int j = 0; j < 4; ++j) {
          STB(OFF_ATT,456, gA*4 + j, w*16 + rA,      l0[j]);
          STB(OFF_ATT,456, gA*4 + j, (w+16)*16 + rA, l1[j]);
        }
      } else {
        f32x4 l0 = {bv1,bv1,bv1,bv1};
        bf16x8 a = LA(OFF_HID,136, rA, gA*8);
        reg_loop<4>(packc, lane,
          [&](int i){ return 604 + w*4 + i; },
          [&](int i, bf16x8 bv8){
            l0 = MFMA_B16(a, bv8, l0);
            if (i + 1 < 4) a = LA(OFF_HID,136, rA, (i+1)*32+gA*8);
          });
        #pragma unroll
        for (int j = 0; j < 4; ++j)
          STB(OFF_ATT,456, gA*4 + j, w*16 + rA, l0[j]);
      }
    }
    __syncthreads();

    // ---- Phase 5: softmax*c_star (w<8) ; nt XP stage for t+1 (w>=8) ----
    if (w < 8) {
      int row = w*2 + (lane >> 5);
      int cb  = lane & 31;
      float v[14];
      float mx = -3.0e38f;
      #pragma unroll
      for (int q = 0; q < 14; ++q) { v[q] = LDB(OFF_ATT,456,row, cb + 32*q); mx = fmaxf(mx, v[q]); }
      #pragma unroll
      for (int mk = 1; mk < 32; mk <<= 1) mx = fmaxf(mx, __shfl_xor(mx, mk));
      float sm = 0.f;
      #pragma unroll
      for (int q = 0; q < 14; ++q) { v[q] = __expf(v[q] - mx); sm += v[q]; }
      #pragma unroll
      for (int mk = 1; mk < 32; mk <<= 1) sm += __shfl_xor(sm, mk);
      float inv = 1.0f / sm;
      #pragma unroll
      for (int q = 0; q < 14; ++q) {
        int c = cb + 32*q;
        float cs = LDB(OFF_CSTAR,456,row,c);
        STB(OFF_ATT,456,row,c, v[q]*inv*cs);
      }
    } else if (t < T_STEPS-1) {
      stage_xp(lds, xp, t+1, n0, tid - 512, 512);
    }
    __syncthreads();

    // ---- Phase 6: att2 layer1 (w8-15, 2 n-tiles); g1/g2 (w0-7) ----
    if (w >= 8) {
      int nb = (w - 8)*2;
      float b0 = biasLds[B_A2H + nb*16 + rA];
      float b1 = biasLds[B_A2H + (nb+1)*16 + rA];
      f32x4 A0 = {b0,b0,b0,b0}, A1 = {b1,b1,b1,b1};
      bf16x8 a = LA(OFF_ATT,456, rA, gA*8);
      reg_loop<28>(packc, lane,
        [&](int i){ int rr = (i >= 14) ? 1 : 0; int s = i - (rr ? 14 : 0); return 716 + (nb+rr)*14 + s; },
        [&](int i, bf16x8 bv8){
          if (i < 14) A0 = MFMA_B16(a, bv8, A0); else A1 = MFMA_B16(a, bv8, A1);
          if (i + 1 < 28) {
            int ns = (i + 1 < 14) ? (i + 1) : (i + 1 - 14);
            a = LA(OFF_ATT,456, rA, ns*32+gA*8);
          }
        });
      #pragma unroll
      for (int j = 0; j < 4; ++j) {
        STB(OFF_HID,264, gA*4 + j, nb*16 + rA,     fmaxf(A0[j], 0.f));
        STB(OFF_HID,264, gA*4 + j, (nb+1)*16 + rA, fmaxf(A1[j], 0.f));
      }
    } else {
      int which = w >> 2;
      int n = w & 3;
      int tbq = which ? 1076 : 1004;
      int bb  = which ? B_G2H : B_G1H;
      int oo  = which ? OFF_G2H : OFF_G1H;
      float bv = biasLds[bb + n*16 + rA];
      f32x4 A0 = {bv,bv,bv,bv};
      bf16x8 a = LA(OFF_ATT,456, rA, gA*8);
      reg_loop<18>(packc, lane,
        [&](int i){ return tbq + n*18 + i; },
        [&](int i, bf16x8 bv8){
          A0 = MFMA_B16(a, bv8, A0);
          if (i + 1 < 18) {
            a = (i + 1 < 14) ? LA(OFF_ATT,456, rA, (i+1)*32+gA*8)
                             : LA(OFF_FEATS,360, rA, 224 + (i+1-14)*32 + gA*8);
          }
        });
      #pragma unroll
      for (int j = 0; j < 4; ++j)
        STB(oo,72, gA*4 + j, n*16 + rA, fmaxf(A0[j], 0.f));
    }
    __syncthreads();

    // ---- Phase 7: att2 layer2 + gammas + mem ----
    if (w < 8) {
      int n = w;
      float bc = biasLds[B_CHAT + n*16 + rA];
      float b1 = biasLds[B_GM1  + n*16 + rA];
      float b2 = biasLds[B_GM2  + n*16 + rA];
      f32x4 cc0={bc,bc,bc,bc};
      f32x4 g10={b1,b1,b1,b1};
      f32x4 g20={b2,b2,b2,b2};
      bf16x8 a = LA(OFF_HID,264, rA, gA*8);
      reg_loop<12>(packc, lane,
        [&](int i){
          if (i < 8)  return 940 + n*8 + i;
          if (i < 10) return 1148 + n*2 + (i - 8);
          return 1164 + n*2 + (i - 10);
        },
        [&](int i, bf16x8 bv8){
          if (i < 8)       cc0 = MFMA_B16(a, bv8, cc0);
          else if (i < 10) g10 = MFMA_B16(a, bv8, g10);
          else             g20 = MFMA_B16(a, bv8, g20);
          if (i + 1 < 8)        a = LA(OFF_HID,264, rA, (i+1)*32+gA*8);
          else if (i + 1 == 8)  a = LA(OFF_G1H,72, rA, gA*8);
          else if (i + 1 == 9)  a = LA(OFF_G1H,72, rA, 32+gA*8);
          else if (i + 1 == 10) a = LA(OFF_G2H,72, rA, gA*8);
          else if (i + 1 == 11) a = LA(OFF_G2H,72, rA, 32+gA*8);
        });
      #pragma unroll
      for (int j = 0; j < 4; ++j) {
        float ch = tanh_(cc0[j]), ga = sigm(g10[j]), gb = sigm(g20[j]);
        float mn = ga*mreg[j] + gb*ch;
        mreg[j] = mn;
        STB(OFF_FEATS,360, gA*4 + j, 224 + n*16 + rA, mn);
      }
    }
    __syncthreads();

    // ---- Phase 8: out layer1 ----
    if (w < 4) {
      int n = w;
      float bv = biasLds[B_OUTH + n*16 + rA];
      f32x4 a0v = {bv,bv,bv,bv};
      bf16x8 a = LA(OFF_FEATS,360, rA, gA*8);
      reg_loop<11>(packc, lane,
        [&](int i){ return 1180 + n*11 + i; },
        [&](int i, bf16x8 bv8){
          a0v = MFMA_B16(a, bv8, a0v);
          if (i + 1 < 11) a = LA(OFF_FEATS,360, rA, (i+1)*32+gA*8);
        });
      #pragma unroll
      for (int j = 0; j < 4; ++j)
        STB(OFF_HID,72, gA*4 + j, n*16 + rA, fmaxf(a0v[j], 0.f));
    }
    __syncthreads();
  }

  // ---- Final out2 for t = 127 ----
  if (w == 15) {
    float bv = biasLds[B_OUT2];
    f32x4 oa0 = {bv,bv,bv,bv};
    oa0 = MFMA_B16(LA(OFF_HID,72, rA, gA*8),      ow0, oa0);
    oa0 = MFMA_B16(LA(OFF_HID,72, rA, 32 + gA*8), ow1, oa0);
    if (rA == 0) {
      #pragma unroll
      for (int j = 0; j < 4; ++j)
        __builtin_nontemporal_store(oa0[j], &out[(size_t)(n0 + gA*4 + j)*T_STEPS + 127]);
    }
  }
}

extern "C" void kernel_launch(void* const* d_in, const int* in_sizes, int n_in,
                              void* d_out, int out_size, void* d_ws, size_t ws_size,
                              hipStream_t stream) {
  (void)in_sizes; (void)n_in; (void)out_size; (void)ws_size;
  PP P;
  for (int i = 0; i < 35; ++i) P.p[i] = (const float*)d_in[i];
  unsigned short* pack = (unsigned short*)d_ws;
  float* bias = (float*)((char*)d_ws + PACK_BYTES);
  unsigned short* xp = (unsigned short*)((char*)d_ws + PACK_BYTES + 16384);

  hipLaunchKernelGGL(pack_kernel, dim3(320), dim3(256), 0, stream, P, pack, bias);
  hipLaunchKernelGGL(xproj_kernel, dim3(2048), dim3(1024), 0, stream,
                     P.p[0], P.p[1], P.p[2], pack, xp);
  hipLaunchKernelGGL(fused_kernel, dim3(128), dim3(1024), 0, stream,
                     pack, bias, xp, (float*)d_out);
}

// Round 18
// 3861.066 us; speedup vs baseline: 1.3748x; 1.3748x over previous
//
#include <hip/hip_runtime.h>

// ---------------------------------------------------------------------------
// Fused recurrent multimodal net. T=128, N=2048. 128 blocks x 16 rows.
// Round 17: r15 base + 48KB LDS weight cache on P6 (att2-l1 ks 0..2 for all
// 16 n-tiles) -> P6 ring 28->22/wave. r16's persistent-VGPR weights are
// DROPPED (64-arch-VGPR cap forced rematerialization: FETCH 0.67->3.0GB).
// Bytes/step 902 -> 854KB; phase critical path 85 -> 79 tiles.
// ---------------------------------------------------------------------------

#define T_STEPS 128

typedef __attribute__((ext_vector_type(8))) short bf16x8;
typedef __attribute__((ext_vector_type(4))) float f32x4;
typedef __attribute__((ext_vector_type(2))) unsigned long long ull2;

#define MFMA_B16(a,b,c) __builtin_amdgcn_mfma_f32_16x16x32_bf16((a),(b),(c),0,0,0)

__device__ __forceinline__ unsigned short f2b(float v) {
  union { float f; unsigned u; } x; x.f = v;
  unsigned r = x.u + 0x7fffu + ((x.u >> 16) & 1u);
  return (unsigned short)(r >> 16);
}
__device__ __forceinline__ float b2f(unsigned short u) {
  union { unsigned u; float f; } x; x.u = ((unsigned)u) << 16; return x.f;
}
__device__ __forceinline__ float sigm(float x){ return 1.0f/(1.0f + __expf(-x)); }
__device__ __forceinline__ float tanh_(float x){ return 1.0f - 2.0f/(1.0f + __expf(2.0f*x)); }

// ---- core LDS layout ----
#define OFF_XL     0
#define OFF_XA     10496
#define OFF_XI     13824
#define OFF_CSTAR  16128
#define OFF_ATT    30720
#define OFF_HID    45312
#define OFF_G1H    53760
#define OFF_G2H    56064
#define OFF_FEATS  58368
#define OFF_BIAS   69888
#define OFF_XP     79368    // 16 x 968 bf16 (30976 B)
#define OFF_WC     110344   // 48 tiles x 1KB weight cache (att2-l1 ks<3)
#define LDS_BYTES  159496   // <= 160KiB; 1 block/CU

// ---- bias layout ----
#define BG_LIN 0
#define BG_AC  384
#define BG_IM  576
#define B_A1H  960
#define B_LOG  1088
#define B_A2H  1536
#define B_CHAT 1792
#define B_G1H  1920
#define B_G2H  1984
#define B_GM1  2048
#define B_GM2  2176
#define B_OUTH 2304
#define B_OUT2 2368
#define N_BIAS 2369

#define N_TILES 1718
#define PACK_BYTES ((size_t)N_TILES * 1024)
#define XP_ELEMS ((size_t)262144 * 960)
#define XP_BYTES (XP_ELEMS * 2)

#define LA(off,st,row,kk)  (*(const bf16x8*)(lds + (off) + ((((row)*(st)) + (kk)) << 1)))
#define LB(tile)           (*(const bf16x8*)(packc + (((size_t)(tile)) << 10) + (lane << 4)))
#define LW(slot)           (*(const bf16x8*)(lds + OFF_WC + (((size_t)(slot)) << 10) + (lane << 4)))
#define STB(off,st,row,col,v) (*(unsigned short*)(lds + (off) + ((((row)*(st)) + (col)) << 1)) = f2b(v))
#define LDB(off,st,row,col)   b2f(*(const unsigned short*)(lds + (off) + ((((row)*(st)) + (col)) << 1)))

struct PP { const float* p[35]; };

// ---------------------------------------------------------------------------
// Register async-pipeline primitives (depth-8, issue-1/consume-1; r8/r12)
// ---------------------------------------------------------------------------
__device__ __forceinline__ void vmw(int n) {
  switch (n) {
    case 0: asm volatile("s_waitcnt vmcnt(0)"); break;
    case 1: asm volatile("s_waitcnt vmcnt(1)"); break;
    case 2: asm volatile("s_waitcnt vmcnt(2)"); break;
    case 3: asm volatile("s_waitcnt vmcnt(3)"); break;
    case 4: asm volatile("s_waitcnt vmcnt(4)"); break;
    case 5: asm volatile("s_waitcnt vmcnt(5)"); break;
    case 6: asm volatile("s_waitcnt vmcnt(6)"); break;
    default: asm volatile("s_waitcnt vmcnt(7)"); break;
  }
  __builtin_amdgcn_sched_barrier(0);
}

#define ISSUE_B(dst, tile)                                                   \
  { unsigned off_ = (((unsigned)(tile)) << 10) + ((unsigned)lane << 4);      \
    asm volatile("global_load_dwordx4 %0, %1, %2"                            \
                 : "=v"(dst) : "v"(off_), "s"(packc)); }

template<int NTT, class FT, class FB>
__device__ __forceinline__ void reg_loop(const char* packc, int lane,
                                         FT&& tile_of, FB&& body)
{
  constexpr int D = (NTT < 8) ? NTT : 8;
  bf16x8 b[8];
  #pragma unroll
  for (int i = 0; i < D; ++i) ISSUE_B(b[i], tile_of(i));
  #pragma unroll
  for (int i = 0; i < NTT; ++i) {
    vmw((NTT-1-i) < 7 ? (NTT-1-i) : 7);
    body(i, b[i & 7]);
    __builtin_amdgcn_sched_barrier(0);
    if (i + 8 < NTT) ISSUE_B(b[i & 7], tile_of(i + 8));
  }
}

// ---------------------------------------------------------------------------
// Pack kernel (r12/r15, unchanged)
// ---------------------------------------------------------------------------
__device__ __forceinline__ float gate_src(const float* Wih, const float* Whh,
                                          int H, int din, int nksx, int col, int k)
{
  int blk = col >> 6, gate = (col >> 4) & 3, u = col & 15;
  int unit = blk*16 + u;
  if (unit >= H) return 0.f;
  int row = gate*H + unit;
  int xk = nksx*32;
  if (k < xk) return (k < din) ? Wih[row*din + k] : 0.f;
  int kk = k - xk;
  return (kk < H) ? Whh[row*H + kk] : 0.f;
}
__device__ __forceinline__ float gate_h(const float* Whh, int H, int col, int k)
{
  int blk = col >> 6, gate = (col >> 4) & 3, u = col & 15;
  int unit = blk*16 + u;
  if (unit >= H || k >= H) return 0.f;
  return Whh[(gate*H + unit)*H + k];
}
__device__ __forceinline__ float gate_x(const float* Wih, int H, int din, int col, int k)
{
  int blk = col >> 6, gate = (col >> 4) & 3, u = col & 15;
  int unit = blk*16 + u;
  if (unit >= H || k >= din) return 0.f;
  return Wih[(gate*H + unit)*din + k];
}
__device__ __forceinline__ float plain_src(const float* W, int nout, int kdim, int col, int k)
{
  return (col < nout && k < kdim) ? W[col*kdim + k] : 0.f;
}

__global__ __launch_bounds__(256) void pack_kernel(PP P, unsigned short* __restrict__ pack,
                                                   float* __restrict__ bias)
{
  int tid = blockIdx.x*blockDim.x + threadIdx.x;
  int wv = tid >> 6, lane = tid & 63;
  int nw = (gridDim.x*blockDim.x) >> 6;
  int c = lane & 15, kg = lane >> 4;

  for (int tile = wv; tile < N_TILES; tile += nw) {
    unsigned short* dst = pack + ((size_t)tile << 9) + lane*8;
    #pragma unroll
    for (int i = 0; i < 8; ++i) {
      int r = tile; int nt, ks; float v; int kk;
      if (r < 312)       { nt=r/13; ks=r-nt*13; kk=ks*32+kg*8+i; v = gate_src(P.p[3], P.p[4], 88,300,10, nt*16+c, kk); }
      else if (r < 372)  { r-=312; nt=r/5;  ks=r-nt*5;  kk=ks*32+kg*8+i; v = gate_src(P.p[7], P.p[8], 48, 74, 3, nt*16+c, kk); }
      else if (r < 492)  { r-=372; nt=r/5;  ks=r-nt*5;  kk=ks*32+kg*8+i; v = gate_src(P.p[11],P.p[12],88, 35, 2, nt*16+c, kk); }
      else if (r < 604)  { r-=492; nt=r/14; ks=r-nt*14; kk=ks*32+kg*8+i; v = plain_src(P.p[15],128,448, nt*16+c, kk); }
      else if (r < 716)  { r-=604; nt=r/4;  ks=r-nt*4;  kk=ks*32+kg*8+i; v = plain_src(P.p[17],448,128, nt*16+c, kk); }
      else if (r < 940)  { r-=716; nt=r/14; ks=r-nt*14; kk=ks*32+kg*8+i; v = plain_src(P.p[19],256,448, nt*16+c, kk); }
      else if (r < 1004) { r-=940; nt=r/8;  ks=r-nt*8;  kk=ks*32+kg*8+i; v = plain_src(P.p[21],128,256, nt*16+c, kk); }
      else if (r < 1076) { r-=1004; nt=r/18; ks=r-nt*18; kk=ks*32+kg*8+i; v = plain_src(P.p[23], 64,576, nt*16+c, kk); }
      else if (r < 1148) { r-=1076; nt=r/18; ks=r-nt*18; kk=ks*32+kg*8+i; v = plain_src(P.p[27], 64,576, nt*16+c, kk); }
      else if (r < 1164) { r-=1148; nt=r/2;  ks=r-nt*2;  kk=ks*32+kg*8+i; v = plain_src(P.p[25],128, 64, nt*16+c, kk); }
      else if (r < 1180) { r-=1164; nt=r/2;  ks=r-nt*2;  kk=ks*32+kg*8+i; v = plain_src(P.p[29],128, 64, nt*16+c, kk); }
      else if (r < 1224) { r-=1180; nt=r/11; ks=r-nt*11; kk=ks*32+kg*8+i; v = plain_src(P.p[31], 64,352, nt*16+c, kk); }
      else if (r < 1226) { r-=1224; ks=r;    kk=ks*32+kg*8+i; v = plain_src(P.p[33],  1, 64, c, kk); }
      else if (r < 1298) { r-=1226; nt=r/3;  ks=r-nt*3;  kk=ks*32+kg*8+i; v = gate_h(P.p[4], 88, nt*16+c, kk); }
      else if (r < 1322) { r-=1298; nt=r/2;  ks=r-nt*2;  kk=ks*32+kg*8+i; v = gate_h(P.p[8], 48, nt*16+c, kk); }
      else if (r < 1394) { r-=1322; nt=r/3;  ks=r-nt*3;  kk=ks*32+kg*8+i; v = gate_h(P.p[12],88, nt*16+c, kk); }
      else if (r < 1634) { r-=1394; nt=r/10; ks=r-nt*10; kk=ks*32+kg*8+i; v = gate_x(P.p[3], 88,300, nt*16+c, kk); }
      else if (r < 1670) { r-=1634; nt=r/3;  ks=r-nt*3;  kk=ks*32+kg*8+i; v = gate_x(P.p[7], 48, 74, nt*16+c, kk); }
      else               { r-=1670; nt=r/2;  ks=r-nt*2;  kk=ks*32+kg*8+i; v = gate_x(P.p[11],88, 35, nt*16+c, kk); }
      dst[i] = f2b(v);
    }
  }

  int NT = gridDim.x*blockDim.x;
  for (int b = tid; b < N_BIAS; b += NT) {
    float v; int r = b;
    if (r < 384)       { int blk=r>>6, g=(r>>4)&3, u=r&15, un=blk*16+u; v = (un<88) ? P.p[5][g*88+un] + P.p[6][g*88+un]  : 0.f; }
    else if (r < 576)  { r-=384; int blk=r>>6, g=(r>>4)&3, u=r&15, un=blk*16+u; v = (un<48) ? P.p[9][g*48+un] + P.p[10][g*48+un] : 0.f; }
    else if (r < 960)  { r-=576; int blk=r>>6, g=(r>>4)&3, u=r&15, un=blk*16+u; v = (un<88) ? P.p[13][g*88+un]+ P.p[14][g*88+un] : 0.f; }
    else if (r < 1088) v = P.p[16][r-960];
    else if (r < 1536) v = P.p[18][r-1088];
    else if (r < 1792) v = P.p[20][r-1536];
    else if (r < 1920) v = P.p[22][r-1792];
    else if (r < 1984) v = P.p[24][r-1920];
    else if (r < 2048) v = P.p[28][r-1984];
    else if (r < 2176) v = P.p[26][r-2048];
    else if (r < 2304) v = P.p[30][r-2176];
    else if (r < 2368) v = P.p[32][r-2304];
    else               v = P.p[34][0];
    bias[b] = v;
  }
}

// ---------------------------------------------------------------------------
// XP pre-pass (r12, unchanged)
// ---------------------------------------------------------------------------
__global__ __launch_bounds__(1024) void xproj_kernel(
    const float* __restrict__ xlin, const float* __restrict__ xac,
    const float* __restrict__ xim, const unsigned short* __restrict__ pack,
    unsigned short* __restrict__ xp)
{
  __shared__ alignas(16) char slds[81920];
  const char* packc = (const char*)pack;
  const int tid = threadIdx.x, lane = tid & 63, w = tid >> 6;
  const int rA = lane & 15, gA = lane >> 4;
  const int mt = w & 7, half = w >> 3;
  const size_t m0 = (size_t)blockIdx.x * 128;
  const int mr = mt * 16;

  for (int p = tid; p < 9600; p += 1024) {
    int row = p/75, d = p - row*75;
    float4 v = *(const float4*)(xlin + (m0+row)*300 + d*4);
    unsigned long long u = (unsigned long long)f2b(v.x)
      | ((unsigned long long)f2b(v.y) << 16)
      | ((unsigned long long)f2b(v.z) << 32)
      | ((unsigned long long)f2b(v.w) << 48);
    *(unsigned long long*)(slds + (((size_t)row*320 + d*4) << 1)) = u;
  }
  for (int p = tid; p < 1280; p += 1024) {
    int row = p/10, cc = 300 + 2*(p - row*10);
    *(unsigned*)(slds + (((size_t)row*320 + cc) << 1)) = 0;
  }
  __syncthreads();
  for (int blk = half*3; blk < half*3 + 3; ++blk) {
    #pragma unroll
    for (int q = 0; q < 4; ++q) {
      f32x4 acc = {0.f,0.f,0.f,0.f};
      int nt = blk*4 + q;
      bf16x8 a = *(const bf16x8*)(slds + ((((mr+rA)*320) + gA*8) << 1));
      reg_loop<10>(packc, lane,
        [&](int i){ return 1394 + nt*10 + i; },
        [&](int i, bf16x8 bv){
          acc = MFMA_B16(a, bv, acc);
          if (i + 1 < 10) a = *(const bf16x8*)(slds + ((((mr+rA)*320) + (i+1)*32 + gA*8) << 1));
        });
      #pragma unroll
      for (int j = 0; j < 4; ++j)
        xp[(m0 + mr + gA*4 + j)*960 + blk*64 + q*16 + rA] = f2b(acc[j]);
    }
  }
  __syncthreads();

  for (int p = tid; p < 4736; p += 1024) {
    int row = p/37, d = p - row*37;
    float2 v = *(const float2*)(xac + (m0+row)*74 + d*2);
    unsigned uu = (unsigned)f2b(v.x) | ((unsigned)f2b(v.y) << 16);
    *(unsigned*)(slds + (((size_t)row*96 + d*2) << 1)) = uu;
  }
  for (int p = tid; p < 1408; p += 1024) {
    int row = p/11, cc = 74 + 2*(p - row*11);
    *(unsigned*)(slds + (((size_t)row*96 + cc) << 1)) = 0;
  }
  __syncthreads();
  if (half == 0) {
    for (int blk = 0; blk < 3; ++blk) {
      #pragma unroll
      for (int q = 0; q < 4; ++q) {
        f32x4 acc = {0.f,0.f,0.f,0.f};
        int nt = blk*4 + q;
        bf16x8 a = *(const bf16x8*)(slds + ((((mr+rA)*96) + gA*8) << 1));
        reg_loop<3>(packc, lane,
          [&](int i){ return 1634 + nt*3 + i; },
          [&](int i, bf16x8 bv){
            acc = MFMA_B16(a, bv, acc);
            if (i + 1 < 3) a = *(const bf16x8*)(slds + ((((mr+rA)*96) + (i+1)*32 + gA*8) << 1));
          });
        #pragma unroll
        for (int j = 0; j < 4; ++j)
          xp[(m0 + mr + gA*4 + j)*960 + 384 + blk*64 + q*16 + rA] = f2b(acc[j]);
      }
    }
  }
  __syncthreads();

  for (int p = tid; p < 4480; p += 1024) {
    int row = p/35, d = p - row*35;
    *(unsigned short*)(slds + (((size_t)row*64 + d) << 1)) = f2b(xim[(m0+row)*35 + d]);
  }
  for (int p = tid; p < 3712; p += 1024) {
    int row = p/29, cc = 35 + (p - row*29);
    *(unsigned short*)(slds + (((size_t)row*64 + cc) << 1)) = 0;
  }
  __syncthreads();
  if (half == 1) {
    for (int blk = 0; blk < 6; ++blk) {
      #pragma unroll
      for (int q = 0; q < 4; ++q) {
        f32x4 acc = {0.f,0.f,0.f,0.f};
        int nt = blk*4 + q;
        bf16x8 a = *(const bf16x8*)(slds + ((((mr+rA)*64) + gA*8) << 1));
        reg_loop<2>(packc, lane,
          [&](int i){ return 1670 + nt*2 + i; },
          [&](int i, bf16x8 bv){
            acc = MFMA_B16(a, bv, acc);
            if (i + 1 < 2) a = *(const bf16x8*)(slds + ((((mr+rA)*64) + 32 + gA*8) << 1));
          });
        #pragma unroll
        for (int j = 0; j < 4; ++j)
          xp[(m0 + mr + gA*4 + j)*960 + 576 + blk*64 + q*16 + rA] = f2b(acc[j]);
      }
    }
  }
}

// ---------------------------------------------------------------------------
// Main fused kernel (r15 structure + 48KB LDS weight cache on P6)
// ---------------------------------------------------------------------------
template<int NKS>
__device__ __forceinline__ void gate_reg_h(f32x4 acc[4], const char* lds, const char* packc,
    int lane, int rA, int gA, int hsec, int tb)
{
  bf16x8 a;
  reg_loop<NKS*4>(packc, lane,
    [&](int i){ return tb + (i & 3)*NKS + (i >> 2); },
    [&](int i, bf16x8 bv){
      int q = i & 3, s = i >> 2;
      if (q == 0) a = LA(OFF_FEATS, 360, rA, hsec + s*32 + gA*8);
      acc[q] = MFMA_B16(a, bv, acc[q]);
    });
}

__device__ __forceinline__ void stage_xp(char* lds, const unsigned short* __restrict__ xp,
                                         int t, int n0, int tid0, int nthr)
{
  const size_t base = ((size_t)t*2048 + n0)*960;
  for (int q = tid0; q < 1920; q += nthr) {
    int row = q/120, ch = q - row*120;
    ull2 v = __builtin_nontemporal_load((const ull2*)(xp + base + (size_t)row*960 + ch*8));
    *(ull2*)(lds + OFF_XP + (((size_t)row*968 + ch*8) << 1)) = v;
  }
}

__global__ __launch_bounds__(1024) void fused_kernel(
    const unsigned short* __restrict__ pack, const float* __restrict__ biasg,
    const unsigned short* __restrict__ xp, float* __restrict__ out)
{
  __shared__ alignas(16) char lds[LDS_BYTES];
  const char* packc = (const char*)pack;
  const int tid  = threadIdx.x;
  const int lane = tid & 63;
  const int w    = tid >> 6;
  const int rA   = lane & 15;
  const int gA   = lane >> 4;
  const int n0   = blockIdx.x * 16;
  float* biasLds = (float*)(lds + OFF_BIAS);

  for (int i = tid; i < (OFF_BIAS >> 2); i += 1024) ((int*)lds)[i] = 0;
  __syncthreads();
  for (int i = tid; i < N_BIAS; i += 1024) biasLds[i] = biasg[i];
  stage_xp(lds, xp, 0, n0, tid, 1024);
  // ---- preload 48KB LDS weight cache: att2-l1 tiles (716 + n*14 + i), i<3 --
  for (int idx = tid; idx < 48*64; idx += 1024) {
    int slot = idx >> 6, l = idx & 63;
    int nn = slot / 3, ii = slot - nn*3;
    int tile = 716 + nn*14 + ii;
    bf16x8 v = *(const bf16x8*)(packc + ((size_t)tile << 10) + (l << 4));
    *(bf16x8*)(lds + OFF_WC + ((size_t)slot << 10) + (l << 4)) = v;
  }
  __syncthreads();

  float cst[4]  = {};
  float mreg[4] = {};

  for (int t = 0; t < T_STEPS; ++t) {
    // ---- Phase 1: gate matmuls (w0..14, h-only, XP-init); w15: out2(t-1) ----
    f32x4 gacc[4];
    if (w == 15) {
      if (t > 0) {
        float bv = biasLds[B_OUT2];
        f32x4 oa0 = {bv,bv,bv,bv};
        bf16x8 as[2], bs[2];
        #pragma unroll
        for (int s = 0; s < 2; ++s) { bs[s] = LB(1224 + s); as[s] = LA(OFF_HID,72, rA, s*32+gA*8); }
        #pragma unroll
        for (int s = 0; s < 2; ++s) oa0 = MFMA_B16(as[s], bs[s], oa0);
        if (rA == 0) {
          #pragma unroll
          for (int j = 0; j < 4; ++j)
            __builtin_nontemporal_store(oa0[j], &out[(size_t)(n0 + gA*4 + j)*T_STEPS + (t-1)]);
        }
      }
    } else {
      int blk, tb, nks, hsec, bb, cb;
      if (w < 6)      { blk=w;   tb=1226+w*12;      nks=3; hsec=0;   bb=BG_LIN; cb=0   + w*64; }
      else if (w < 9) { blk=w-6; tb=1298+(w-6)*8;   nks=2; hsec=88;  bb=BG_AC;  cb=384 + (w-6)*64; }
      else            { blk=w-9; tb=1322+(w-9)*12;  nks=3; hsec=136; bb=BG_IM;  cb=576 + (w-9)*64; }
      #pragma unroll
      for (int q = 0; q < 4; ++q) {
        float bv = biasLds[bb + blk*64 + q*16 + rA];
        #pragma unroll
        for (int j = 0; j < 4; ++j) {
          int row = gA*4 + j;
          float xv = b2f(*(const unsigned short*)(lds + OFF_XP + (((size_t)row*968 + cb + q*16 + rA) << 1)));
          gacc[q][j] = bv + xv;
        }
      }
      if (nks == 3) gate_reg_h<3>(gacc, lds, packc, lane, rA, gA, hsec, tb);
      else          gate_reg_h<2>(gacc, lds, packc, lane, rA, gA, hsec, tb);
    }
    __syncthreads();

    // ---- Phase 2: LSTM elementwise ----
    if (w < 15) {
      int blk, hsec, H;
      if (w < 6)      { blk=w;   hsec=0;   H=88; }
      else if (w < 9) { blk=w-6; hsec=88;  H=48; }
      else            { blk=w-9; hsec=136; H=88; }
      int unit = blk*16 + rA;
      if (unit < H) {
        #pragma unroll
        for (int j = 0; j < 4; ++j) {
          float iv = sigm (gacc[0][j]);
          float fv = sigm (gacc[1][j]);
          float gv = tanh_(gacc[2][j]);
          float ov = sigm (gacc[3][j]);
          float cp = cst[j];
          float cn = fv*cp + iv*gv;
          float hn = ov*tanh_(cn);
          cst[j] = cn;
          int row = gA*4 + j;
          STB(OFF_CSTAR,456, row, hsec + unit,        cp);
          STB(OFF_CSTAR,456, row, 224 + hsec + unit,  cn);
          STB(OFF_FEATS,360, row, hsec + unit,        hn);
        }
      }
    }
    __syncthreads();

    // ---- Phase 3: att1 layer1 ----
    if (w < 8) {
      int n = w;
      float bv = biasLds[B_A1H + n*16 + rA];
      f32x4 a0v = {bv,bv,bv,bv};
      bf16x8 a = LA(OFF_CSTAR,456, rA, gA*8);
      reg_loop<14>(packc, lane,
        [&](int i){ return 492 + n*14 + i; },
        [&](int i, bf16x8 bv8){
          a0v = MFMA_B16(a, bv8, a0v);
          if (i + 1 < 14) a = LA(OFF_CSTAR,456, rA, (i+1)*32+gA*8);
        });
      #pragma unroll
      for (int j = 0; j < 4; ++j)
        STB(OFF_HID,136, gA*4 + j, n*16 + rA, fmaxf(a0v[j], 0.f));
    }
    __syncthreads();

    // ---- Phase 4: att1 layer2 -> logits ----
    {
      float bv1 = biasLds[B_LOG + w*16 + rA];
      if (w < 12) {
        float bv2 = biasLds[B_LOG + (w+16)*16 + rA];
        f32x4 l0 = {bv1,bv1,bv1,bv1}, l1 = {bv2,bv2,bv2,bv2};
        bf16x8 a = LA(OFF_HID,136, rA, gA*8);
        reg_loop<8>(packc, lane,
          [&](int i){ int tau = (i < 4) ? w : (w + 16); return 604 + tau*4 + (i & 3); },
          [&](int i, bf16x8 bv8){
            if (i < 4) l0 = MFMA_B16(a, bv8, l0); else l1 = MFMA_B16(a, bv8, l1);
            if (i + 1 < 8) a = LA(OFF_HID,136, rA, ((i+1)&3)*32+gA*8);
          });
        #pragma unroll
        for (int j = 0; j < 4; ++j) {
          STB(OFF_ATT,456, gA*4 + j, w*16 + rA,      l0[j]);
          STB(OFF_ATT,456, gA*4 + j, (w+16)*16 + rA, l1[j]);
        }
      } else {
        f32x4 l0 = {bv1,bv1,bv1,bv1};
        bf16x8 a = LA(OFF_HID,136, rA, gA*8);
        reg_loop<4>(packc, lane,
          [&](int i){ return 604 + w*4 + i; },
          [&](int i, bf16x8 bv8){
            l0 = MFMA_B16(a, bv8, l0);
            if (i + 1 < 4) a = LA(OFF_HID,136, rA, (i+1)*32+gA*8);
          });
        #pragma unroll
        for (int j = 0; j < 4; ++j)
          STB(OFF_ATT,456, gA*4 + j, w*16 + rA, l0[j]);
      }
    }
    __syncthreads();

    // ---- Phase 5: softmax*c_star (w<8) ; nt XP stage for t+1 (w>=8) ----
    if (w < 8) {
      int row = w*2 + (lane >> 5);
      int cb  = lane & 31;
      float v[14];
      float mx = -3.0e38f;
      #pragma unroll
      for (int q = 0; q < 14; ++q) { v[q] = LDB(OFF_ATT,456,row, cb + 32*q); mx = fmaxf(mx, v[q]); }
      #pragma unroll
      for (int mk = 1; mk < 32; mk <<= 1) mx = fmaxf(mx, __shfl_xor(mx, mk));
      float sm = 0.f;
      #pragma unroll
      for (int q = 0; q < 14; ++q) { v[q] = __expf(v[q] - mx); sm += v[q]; }
      #pragma unroll
      for (int mk = 1; mk < 32; mk <<= 1) sm += __shfl_xor(sm, mk);
      float inv = 1.0f / sm;
      #pragma unroll
      for (int q = 0; q < 14; ++q) {
        int c = cb + 32*q;
        float cs = LDB(OFF_CSTAR,456,row,c);
        STB(OFF_ATT,456,row,c, v[q]*inv*cs);
      }
    } else if (t < T_STEPS-1) {
      stage_xp(lds, xp, t+1, n0, tid - 512, 512);
    }
    __syncthreads();

    // ---- Phase 6: att2 layer1 (w8-15: 3+3 cached, ring 22); g1/g2 (w0-7) ----
    if (w >= 8) {
      int nb = (w - 8)*2;
      float b0 = biasLds[B_A2H + nb*16 + rA];
      float b1 = biasLds[B_A2H + (nb+1)*16 + rA];
      f32x4 A0 = {b0,b0,b0,b0}, A1 = {b1,b1,b1,b1};
      // cached K-slices 0..2 from LDS weight cache
      #pragma unroll
      for (int i = 0; i < 3; ++i) {
        bf16x8 a  = LA(OFF_ATT,456, rA, i*32+gA*8);
        bf16x8 w0 = LW(nb*3 + i);
        bf16x8 w1 = LW((nb+1)*3 + i);
        A0 = MFMA_B16(a, w0, A0);
        A1 = MFMA_B16(a, w1, A1);
      }
      // remaining K-slices 3..13 via global ring
      reg_loop<22>(packc, lane,
        [&](int i){ int rr = (i >= 11) ? 1 : 0; int s = 3 + (rr ? (i - 11) : i); return 716 + (nb+rr)*14 + s; },
        [&](int i, bf16x8 bv8){
          int s = 3 + ((i >= 11) ? (i - 11) : i);
          bf16x8 a = LA(OFF_ATT,456, rA, s*32+gA*8);
          if (i < 11) A0 = MFMA_B16(a, bv8, A0); else A1 = MFMA_B16(a, bv8, A1);
        });
      #pragma unroll
      for (int j = 0; j < 4; ++j) {
        STB(OFF_HID,264, gA*4 + j, nb*16 + rA,     fmaxf(A0[j], 0.f));
        STB(OFF_HID,264, gA*4 + j, (nb+1)*16 + rA, fmaxf(A1[j], 0.f));
      }
    } else {
      int which = w >> 2;
      int n = w & 3;
      int tbq = which ? 1076 : 1004;
      int bb  = which ? B_G2H : B_G1H;
      int oo  = which ? OFF_G2H : OFF_G1H;
      float bv = biasLds[bb + n*16 + rA];
      f32x4 A0 = {bv,bv,bv,bv};
      bf16x8 a = LA(OFF_ATT,456, rA, gA*8);
      reg_loop<18>(packc, lane,
        [&](int i){ return tbq + n*18 + i; },
        [&](int i, bf16x8 bv8){
          A0 = MFMA_B16(a, bv8, A0);
          if (i + 1 < 18) {
            a = (i + 1 < 14) ? LA(OFF_ATT,456, rA, (i+1)*32+gA*8)
                             : LA(OFF_FEATS,360, rA, 224 + (i+1-14)*32 + gA*8);
          }
        });
      #pragma unroll
      for (int j = 0; j < 4; ++j)
        STB(oo,72, gA*4 + j, n*16 + rA, fmaxf(A0[j], 0.f));
    }
    __syncthreads();

    // ---- Phase 7: att2 layer2 + gammas + mem ----
    if (w < 8) {
      int n = w;
      float bc = biasLds[B_CHAT + n*16 + rA];
      float b1 = biasLds[B_GM1  + n*16 + rA];
      float b2 = biasLds[B_GM2  + n*16 + rA];
      f32x4 cc0={bc,bc,bc,bc};
      f32x4 g10={b1,b1,b1,b1};
      f32x4 g20={b2,b2,b2,b2};
      bf16x8 a = LA(OFF_HID,264, rA, gA*8);
      reg_loop<12>(packc, lane,
        [&](int i){
          if (i < 8)  return 940 + n*8 + i;
          if (i < 10) return 1148 + n*2 + (i - 8);
          return 1164 + n*2 + (i - 10);
        },
        [&](int i, bf16x8 bv8){
          if (i < 8)       cc0 = MFMA_B16(a, bv8, cc0);
          else if (i < 10) g10 = MFMA_B16(a, bv8, g10);
          else             g20 = MFMA_B16(a, bv8, g20);
          if (i + 1 < 8)        a = LA(OFF_HID,264, rA, (i+1)*32+gA*8);
          else if (i + 1 == 8)  a = LA(OFF_G1H,72, rA, gA*8);
          else if (i + 1 == 9)  a = LA(OFF_G1H,72, rA, 32+gA*8);
          else if (i + 1 == 10) a = LA(OFF_G2H,72, rA, gA*8);
          else if (i + 1 == 11) a = LA(OFF_G2H,72, rA, 32+gA*8);
        });
      #pragma unroll
      for (int j = 0; j < 4; ++j) {
        float ch = tanh_(cc0[j]), ga = sigm(g10[j]), gb = sigm(g20[j]);
        float mn = ga*mreg[j] + gb*ch;
        mreg[j] = mn;
        STB(OFF_FEATS,360, gA*4 + j, 224 + n*16 + rA, mn);
      }
    }
    __syncthreads();

    // ---- Phase 8: out layer1 ----
    if (w < 4) {
      int n = w;
      float bv = biasLds[B_OUTH + n*16 + rA];
      f32x4 a0v = {bv,bv,bv,bv};
      bf16x8 a = LA(OFF_FEATS,360, rA, gA*8);
      reg_loop<11>(packc, lane,
        [&](int i){ return 1180 + n*11 + i; },
        [&](int i, bf16x8 bv8){
          a0v = MFMA_B16(a, bv8, a0v);
          if (i + 1 < 11) a = LA(OFF_FEATS,360, rA, (i+1)*32+gA*8);
        });
      #pragma unroll
      for (int j = 0; j < 4; ++j)
        STB(OFF_HID,72, gA*4 + j, n*16 + rA, fmaxf(a0v[j], 0.f));
    }
    __syncthreads();
  }

  // ---- Final out2 for t = 127 ----
  if (w == 15) {
    float bv = biasLds[B_OUT2];
    f32x4 oa0 = {bv,bv,bv,bv};
    bf16x8 as[2], bs[2];
    #pragma unroll
    for (int s = 0; s < 2; ++s) { bs[s] = LB(1224 + s); as[s] = LA(OFF_HID,72, rA, s*32+gA*8); }
    #pragma unroll
    for (int s = 0; s < 2; ++s) oa0 = MFMA_B16(as[s], bs[s], oa0);
    if (rA == 0) {
      #pragma unroll
      for (int j = 0; j < 4; ++j)
        __builtin_nontemporal_store(oa0[j], &out[(size_t)(n0 + gA*4 + j)*T_STEPS + 127]);
    }
  }
}

extern "C" void kernel_launch(void* const* d_in, const int* in_sizes, int n_in,
                              void* d_out, int out_size, void* d_ws, size_t ws_size,
                              hipStream_t stream) {
  (void)in_sizes; (void)n_in; (void)out_size; (void)ws_size;
  PP P;
  for (int i = 0; i < 35; ++i) P.p[i] = (const float*)d_in[i];
  unsigned short* pack = (unsigned short*)d_ws;
  float* bias = (float*)((char*)d_ws + PACK_BYTES);
  unsigned short* xp = (unsigned short*)((char*)d_ws + PACK_BYTES + 16384);

  hipLaunchKernelGGL(pack_kernel, dim3(320), dim3(256), 0, stream, P, pack, bias);
  hipLaunchKernelGGL(xproj_kernel, dim3(2048), dim3(1024), 0, stream,
                     P.p[0], P.p[1], P.p[2], pack, xp);
  hipLaunchKernelGGL(fused_kernel, dim3(128), dim3(1024), 0, stream,
                     pack, bias, xp, (float*)d_out);
}

// Round 19
// 3801.753 us; speedup vs baseline: 1.3962x; 1.0156x over previous
//
#include <hip/hip_runtime.h>

// ---------------------------------------------------------------------------
// Fused recurrent multimodal net. T=128, N=2048. 128 blocks x 16 rows.
// Round 18: r17 + reclaim dead x-staging LDS (16.1KB; XPATH never used it)
// -> weight cache 48 -> 64 tiles (att2-l1 ks 0..3 for all 16 n-tiles).
// Bytes/step 854 -> 838KB. Byte-law (r12/r15/r17): fused_time =
// bytes/step / ~12.8 B/cy/CU. This uses the last cacheable LDS byte.
// ---------------------------------------------------------------------------

#define T_STEPS 128

typedef __attribute__((ext_vector_type(8))) short bf16x8;
typedef __attribute__((ext_vector_type(4))) float f32x4;
typedef __attribute__((ext_vector_type(2))) unsigned long long ull2;

#define MFMA_B16(a,b,c) __builtin_amdgcn_mfma_f32_16x16x32_bf16((a),(b),(c),0,0,0)

__device__ __forceinline__ unsigned short f2b(float v) {
  union { float f; unsigned u; } x; x.f = v;
  unsigned r = x.u + 0x7fffu + ((x.u >> 16) & 1u);
  return (unsigned short)(r >> 16);
}
__device__ __forceinline__ float b2f(unsigned short u) {
  union { unsigned u; float f; } x; x.u = ((unsigned)u) << 16; return x.f;
}
__device__ __forceinline__ float sigm(float x){ return 1.0f/(1.0f + __expf(-x)); }
__device__ __forceinline__ float tanh_(float x){ return 1.0f - 2.0f/(1.0f + __expf(2.0f*x)); }

// ---- core LDS layout (x-staging buffers removed; all 16B-aligned) ----
#define OFF_CSTAR  0        // 16 x 456 bf16
#define OFF_ATT    14592    // 16 x 456
#define OFF_HID    29184    // 16 x 264
#define OFF_G1H    37632    // 16 x 72
#define OFF_G2H    39936    // 16 x 72
#define OFF_FEATS  42240    // 16 x 360
#define OFF_BIAS   53760    // 2369 f32 (+pad)
#define OFF_XP     63248    // 16 x 968 bf16 (30976 B)
#define OFF_WC     94224    // 64 tiles x 1KB weight cache (att2-l1 ks<4)
#define LDS_BYTES  159760   // <= 160KiB; >80KB -> 1 block/CU

// ---- bias layout ----
#define BG_LIN 0
#define BG_AC  384
#define BG_IM  576
#define B_A1H  960
#define B_LOG  1088
#define B_A2H  1536
#define B_CHAT 1792
#define B_G1H  1920
#define B_G2H  1984
#define B_GM1  2048
#define B_GM2  2176
#define B_OUTH 2304
#define B_OUT2 2368
#define N_BIAS 2369

#define N_TILES 1718
#define PACK_BYTES ((size_t)N_TILES * 1024)
#define XP_ELEMS ((size_t)262144 * 960)
#define XP_BYTES (XP_ELEMS * 2)

#define LA(off,st,row,kk)  (*(const bf16x8*)(lds + (off) + ((((row)*(st)) + (kk)) << 1)))
#define LB(tile)           (*(const bf16x8*)(packc + (((size_t)(tile)) << 10) + (lane << 4)))
#define LW(slot)           (*(const bf16x8*)(lds + OFF_WC + (((size_t)(slot)) << 10) + (lane << 4)))
#define STB(off,st,row,col,v) (*(unsigned short*)(lds + (off) + ((((row)*(st)) + (col)) << 1)) = f2b(v))
#define LDB(off,st,row,col)   b2f(*(const unsigned short*)(lds + (off) + ((((row)*(st)) + (col)) << 1)))

struct PP { const float* p[35]; };

// ---------------------------------------------------------------------------
// Register async-pipeline primitives (depth-8, issue-1/consume-1; r8/r12)
// ---------------------------------------------------------------------------
__device__ __forceinline__ void vmw(int n) {
  switch (n) {
    case 0: asm volatile("s_waitcnt vmcnt(0)"); break;
    case 1: asm volatile("s_waitcnt vmcnt(1)"); break;
    case 2: asm volatile("s_waitcnt vmcnt(2)"); break;
    case 3: asm volatile("s_waitcnt vmcnt(3)"); break;
    case 4: asm volatile("s_waitcnt vmcnt(4)"); break;
    case 5: asm volatile("s_waitcnt vmcnt(5)"); break;
    case 6: asm volatile("s_waitcnt vmcnt(6)"); break;
    default: asm volatile("s_waitcnt vmcnt(7)"); break;
  }
  __builtin_amdgcn_sched_barrier(0);
}

#define ISSUE_B(dst, tile)                                                   \
  { unsigned off_ = (((unsigned)(tile)) << 10) + ((unsigned)lane << 4);      \
    asm volatile("global_load_dwordx4 %0, %1, %2"                            \
                 : "=v"(dst) : "v"(off_), "s"(packc)); }

template<int NTT, class FT, class FB>
__device__ __forceinline__ void reg_loop(const char* packc, int lane,
                                         FT&& tile_of, FB&& body)
{
  constexpr int D = (NTT < 8) ? NTT : 8;
  bf16x8 b[8];
  #pragma unroll
  for (int i = 0; i < D; ++i) ISSUE_B(b[i], tile_of(i));
  #pragma unroll
  for (int i = 0; i < NTT; ++i) {
    vmw((NTT-1-i) < 7 ? (NTT-1-i) : 7);
    body(i, b[i & 7]);
    __builtin_amdgcn_sched_barrier(0);
    if (i + 8 < NTT) ISSUE_B(b[i & 7], tile_of(i + 8));
  }
}

// ---------------------------------------------------------------------------
// Pack kernel (unchanged)
// ---------------------------------------------------------------------------
__device__ __forceinline__ float gate_src(const float* Wih, const float* Whh,
                                          int H, int din, int nksx, int col, int k)
{
  int blk = col >> 6, gate = (col >> 4) & 3, u = col & 15;
  int unit = blk*16 + u;
  if (unit >= H) return 0.f;
  int row = gate*H + unit;
  int xk = nksx*32;
  if (k < xk) return (k < din) ? Wih[row*din + k] : 0.f;
  int kk = k - xk;
  return (kk < H) ? Whh[row*H + kk] : 0.f;
}
__device__ __forceinline__ float gate_h(const float* Whh, int H, int col, int k)
{
  int blk = col >> 6, gate = (col >> 4) & 3, u = col & 15;
  int unit = blk*16 + u;
  if (unit >= H || k >= H) return 0.f;
  return Whh[(gate*H + unit)*H + k];
}
__device__ __forceinline__ float gate_x(const float* Wih, int H, int din, int col, int k)
{
  int blk = col >> 6, gate = (col >> 4) & 3, u = col & 15;
  int unit = blk*16 + u;
  if (unit >= H || k >= din) return 0.f;
  return Wih[(gate*H + unit)*din + k];
}
__device__ __forceinline__ float plain_src(const float* W, int nout, int kdim, int col, int k)
{
  return (col < nout && k < kdim) ? W[col*kdim + k] : 0.f;
}

__global__ __launch_bounds__(256) void pack_kernel(PP P, unsigned short* __restrict__ pack,
                                                   float* __restrict__ bias)
{
  int tid = blockIdx.x*blockDim.x + threadIdx.x;
  int wv = tid >> 6, lane = tid & 63;
  int nw = (gridDim.x*blockDim.x) >> 6;
  int c = lane & 15, kg = lane >> 4;

  for (int tile = wv; tile < N_TILES; tile += nw) {
    unsigned short* dst = pack + ((size_t)tile << 9) + lane*8;
    #pragma unroll
    for (int i = 0; i < 8; ++i) {
      int r = tile; int nt, ks; float v; int kk;
      if (r < 312)       { nt=r/13; ks=r-nt*13; kk=ks*32+kg*8+i; v = gate_src(P.p[3], P.p[4], 88,300,10, nt*16+c, kk); }
      else if (r < 372)  { r-=312; nt=r/5;  ks=r-nt*5;  kk=ks*32+kg*8+i; v = gate_src(P.p[7], P.p[8], 48, 74, 3, nt*16+c, kk); }
      else if (r < 492)  { r-=372; nt=r/5;  ks=r-nt*5;  kk=ks*32+kg*8+i; v = gate_src(P.p[11],P.p[12],88, 35, 2, nt*16+c, kk); }
      else if (r < 604)  { r-=492; nt=r/14; ks=r-nt*14; kk=ks*32+kg*8+i; v = plain_src(P.p[15],128,448, nt*16+c, kk); }
      else if (r < 716)  { r-=604; nt=r/4;  ks=r-nt*4;  kk=ks*32+kg*8+i; v = plain_src(P.p[17],448,128, nt*16+c, kk); }
      else if (r < 940)  { r-=716; nt=r/14; ks=r-nt*14; kk=ks*32+kg*8+i; v = plain_src(P.p[19],256,448, nt*16+c, kk); }
      else if (r < 1004) { r-=940; nt=r/8;  ks=r-nt*8;  kk=ks*32+kg*8+i; v = plain_src(P.p[21],128,256, nt*16+c, kk); }
      else if (r < 1076) { r-=1004; nt=r/18; ks=r-nt*18; kk=ks*32+kg*8+i; v = plain_src(P.p[23], 64,576, nt*16+c, kk); }
      else if (r < 1148) { r-=1076; nt=r/18; ks=r-nt*18; kk=ks*32+kg*8+i; v = plain_src(P.p[27], 64,576, nt*16+c, kk); }
      else if (r < 1164) { r-=1148; nt=r/2;  ks=r-nt*2;  kk=ks*32+kg*8+i; v = plain_src(P.p[25],128, 64, nt*16+c, kk); }
      else if (r < 1180) { r-=1164; nt=r/2;  ks=r-nt*2;  kk=ks*32+kg*8+i; v = plain_src(P.p[29],128, 64, nt*16+c, kk); }
      else if (r < 1224) { r-=1180; nt=r/11; ks=r-nt*11; kk=ks*32+kg*8+i; v = plain_src(P.p[31], 64,352, nt*16+c, kk); }
      else if (r < 1226) { r-=1224; ks=r;    kk=ks*32+kg*8+i; v = plain_src(P.p[33],  1, 64, c, kk); }
      else if (r < 1298) { r-=1226; nt=r/3;  ks=r-nt*3;  kk=ks*32+kg*8+i; v = gate_h(P.p[4], 88, nt*16+c, kk); }
      else if (r < 1322) { r-=1298; nt=r/2;  ks=r-nt*2;  kk=ks*32+kg*8+i; v = gate_h(P.p[8], 48, nt*16+c, kk); }
      else if (r < 1394) { r-=1322; nt=r/3;  ks=r-nt*3;  kk=ks*32+kg*8+i; v = gate_h(P.p[12],88, nt*16+c, kk); }
      else if (r < 1634) { r-=1394; nt=r/10; ks=r-nt*10; kk=ks*32+kg*8+i; v = gate_x(P.p[3], 88,300, nt*16+c, kk); }
      else if (r < 1670) { r-=1634; nt=r/3;  ks=r-nt*3;  kk=ks*32+kg*8+i; v = gate_x(P.p[7], 48, 74, nt*16+c, kk); }
      else               { r-=1670; nt=r/2;  ks=r-nt*2;  kk=ks*32+kg*8+i; v = gate_x(P.p[11],88, 35, nt*16+c, kk); }
      dst[i] = f2b(v);
    }
  }

  int NT = gridDim.x*blockDim.x;
  for (int b = tid; b < N_BIAS; b += NT) {
    float v; int r = b;
    if (r < 384)       { int blk=r>>6, g=(r>>4)&3, u=r&15, un=blk*16+u; v = (un<88) ? P.p[5][g*88+un] + P.p[6][g*88+un]  : 0.f; }
    else if (r < 576)  { r-=384; int blk=r>>6, g=(r>>4)&3, u=r&15, un=blk*16+u; v = (un<48) ? P.p[9][g*48+un] + P.p[10][g*48+un] : 0.f; }
    else if (r < 960)  { r-=576; int blk=r>>6, g=(r>>4)&3, u=r&15, un=blk*16+u; v = (un<88) ? P.p[13][g*88+un]+ P.p[14][g*88+un] : 0.f; }
    else if (r < 1088) v = P.p[16][r-960];
    else if (r < 1536) v = P.p[18][r-1088];
    else if (r < 1792) v = P.p[20][r-1536];
    else if (r < 1920) v = P.p[22][r-1792];
    else if (r < 1984) v = P.p[24][r-1920];
    else if (r < 2048) v = P.p[28][r-1984];
    else if (r < 2176) v = P.p[26][r-2048];
    else if (r < 2304) v = P.p[30][r-2176];
    else if (r < 2368) v = P.p[32][r-2304];
    else               v = P.p[34][0];
    bias[b] = v;
  }
}

// ---------------------------------------------------------------------------
// XP pre-pass (unchanged)
// ---------------------------------------------------------------------------
__global__ __launch_bounds__(1024) void xproj_kernel(
    const float* __restrict__ xlin, const float* __restrict__ xac,
    const float* __restrict__ xim, const unsigned short* __restrict__ pack,
    unsigned short* __restrict__ xp)
{
  __shared__ alignas(16) char slds[81920];
  const char* packc = (const char*)pack;
  const int tid = threadIdx.x, lane = tid & 63, w = tid >> 6;
  const int rA = lane & 15, gA = lane >> 4;
  const int mt = w & 7, half = w >> 3;
  const size_t m0 = (size_t)blockIdx.x * 128;
  const int mr = mt * 16;

  for (int p = tid; p < 9600; p += 1024) {
    int row = p/75, d = p - row*75;
    float4 v = *(const float4*)(xlin + (m0+row)*300 + d*4);
    unsigned long long u = (unsigned long long)f2b(v.x)
      | ((unsigned long long)f2b(v.y) << 16)
      | ((unsigned long long)f2b(v.z) << 32)
      | ((unsigned long long)f2b(v.w) << 48);
    *(unsigned long long*)(slds + (((size_t)row*320 + d*4) << 1)) = u;
  }
  for (int p = tid; p < 1280; p += 1024) {
    int row = p/10, cc = 300 + 2*(p - row*10);
    *(unsigned*)(slds + (((size_t)row*320 + cc) << 1)) = 0;
  }
  __syncthreads();
  for (int blk = half*3; blk < half*3 + 3; ++blk) {
    #pragma unroll
    for (int q = 0; q < 4; ++q) {
      f32x4 acc = {0.f,0.f,0.f,0.f};
      int nt = blk*4 + q;
      bf16x8 a = *(const bf16x8*)(slds + ((((mr+rA)*320) + gA*8) << 1));
      reg_loop<10>(packc, lane,
        [&](int i){ return 1394 + nt*10 + i; },
        [&](int i, bf16x8 bv){
          acc = MFMA_B16(a, bv, acc);
          if (i + 1 < 10) a = *(const bf16x8*)(slds + ((((mr+rA)*320) + (i+1)*32 + gA*8) << 1));
        });
      #pragma unroll
      for (int j = 0; j < 4; ++j)
        xp[(m0 + mr + gA*4 + j)*960 + blk*64 + q*16 + rA] = f2b(acc[j]);
    }
  }
  __syncthreads();

  for (int p = tid; p < 4736; p += 1024) {
    int row = p/37, d = p - row*37;
    float2 v = *(const float2*)(xac + (m0+row)*74 + d*2);
    unsigned uu = (unsigned)f2b(v.x) | ((unsigned)f2b(v.y) << 16);
    *(unsigned*)(slds + (((size_t)row*96 + d*2) << 1)) = uu;
  }
  for (int p = tid; p < 1408; p += 1024) {
    int row = p/11, cc = 74 + 2*(p - row*11);
    *(unsigned*)(slds + (((size_t)row*96 + cc) << 1)) = 0;
  }
  __syncthreads();
  if (half == 0) {
    for (int blk = 0; blk < 3; ++blk) {
      #pragma unroll
      for (int q = 0; q < 4; ++q) {
        f32x4 acc = {0.f,0.f,0.f,0.f};
        int nt = blk*4 + q;
        bf16x8 a = *(const bf16x8*)(slds + ((((mr+rA)*96) + gA*8) << 1));
        reg_loop<3>(packc, lane,
          [&](int i){ return 1634 + nt*3 + i; },
          [&](int i, bf16x8 bv){
            acc = MFMA_B16(a, bv, acc);
            if (i + 1 < 3) a = *(const bf16x8*)(slds + ((((mr+rA)*96) + (i+1)*32 + gA*8) << 1));
          });
        #pragma unroll
        for (int j = 0; j < 4; ++j)
          xp[(m0 + mr + gA*4 + j)*960 + 384 + blk*64 + q*16 + rA] = f2b(acc[j]);
      }
    }
  }
  __syncthreads();

  for (int p = tid; p < 4480; p += 1024) {
    int row = p/35, d = p - row*35;
    *(unsigned short*)(slds + (((size_t)row*64 + d) << 1)) = f2b(xim[(m0+row)*35 + d]);
  }
  for (int p = tid; p < 3712; p += 1024) {
    int row = p/29, cc = 35 + (p - row*29);
    *(unsigned short*)(slds + (((size_t)row*64 + cc) << 1)) = 0;
  }
  __syncthreads();
  if (half == 1) {
    for (int blk = 0; blk < 6; ++blk) {
      #pragma unroll
      for (int q = 0; q < 4; ++q) {
        f32x4 acc = {0.f,0.f,0.f,0.f};
        int nt = blk*4 + q;
        bf16x8 a = *(const bf16x8*)(slds + ((((mr+rA)*64) + gA*8) << 1));
        reg_loop<2>(packc, lane,
          [&](int i){ return 1670 + nt*2 + i; },
          [&](int i, bf16x8 bv){
            acc = MFMA_B16(a, bv, acc);
            if (i + 1 < 2) a = *(const bf16x8*)(slds + ((((mr+rA)*64) + 32 + gA*8) << 1));
          });
        #pragma unroll
        for (int j = 0; j < 4; ++j)
          xp[(m0 + mr + gA*4 + j)*960 + 576 + blk*64 + q*16 + rA] = f2b(acc[j]);
      }
    }
  }
}

// ---------------------------------------------------------------------------
// Main fused kernel (r17 structure; 64-tile LDS weight cache on P6)
// ---------------------------------------------------------------------------
template<int NKS>
__device__ __forceinline__ void gate_reg_h(f32x4 acc[4], const char* lds, const char* packc,
    int lane, int rA, int gA, int hsec, int tb)
{
  bf16x8 a;
  reg_loop<NKS*4>(packc, lane,
    [&](int i){ return tb + (i & 3)*NKS + (i >> 2); },
    [&](int i, bf16x8 bv){
      int q = i & 3, s = i >> 2;
      if (q == 0) a = LA(OFF_FEATS, 360, rA, hsec + s*32 + gA*8);
      acc[q] = MFMA_B16(a, bv, acc[q]);
    });
}

__device__ __forceinline__ void stage_xp(char* lds, const unsigned short* __restrict__ xp,
                                         int t, int n0, int tid0, int nthr)
{
  const size_t base = ((size_t)t*2048 + n0)*960;
  for (int q = tid0; q < 1920; q += nthr) {
    int row = q/120, ch = q - row*120;
    ull2 v = __builtin_nontemporal_load((const ull2*)(xp + base + (size_t)row*960 + ch*8));
    *(ull2*)(lds + OFF_XP + (((size_t)row*968 + ch*8) << 1)) = v;
  }
}

__global__ __launch_bounds__(1024) void fused_kernel(
    const unsigned short* __restrict__ pack, const float* __restrict__ biasg,
    const unsigned short* __restrict__ xp, float* __restrict__ out)
{
  __shared__ alignas(16) char lds[LDS_BYTES];
  const char* packc = (const char*)pack;
  const int tid  = threadIdx.x;
  const int lane = tid & 63;
  const int w    = tid >> 6;
  const int rA   = lane & 15;
  const int gA   = lane >> 4;
  const int n0   = blockIdx.x * 16;
  float* biasLds = (float*)(lds + OFF_BIAS);

  for (int i = tid; i < (OFF_BIAS >> 2); i += 1024) ((int*)lds)[i] = 0;
  __syncthreads();
  for (int i = tid; i < N_BIAS; i += 1024) biasLds[i] = biasg[i];
  stage_xp(lds, xp, 0, n0, tid, 1024);
  // ---- preload 64KB LDS weight cache: att2-l1 tiles (716 + n*14 + i), i<4 --
  for (int idx = tid; idx < 64*64; idx += 1024) {
    int slot = idx >> 6, l = idx & 63;
    int nn = slot >> 2, ii = slot & 3;
    int tile = 716 + nn*14 + ii;
    bf16x8 v = *(const bf16x8*)(packc + ((size_t)tile << 10) + (l << 4));
    *(bf16x8*)(lds + OFF_WC + ((size_t)slot << 10) + (l << 4)) = v;
  }
  __syncthreads();

  float cst[4]  = {};
  float mreg[4] = {};

  for (int t = 0; t < T_STEPS; ++t) {
    // ---- Phase 1: gate matmuls (w0..14, h-only, XP-init); w15: out2(t-1) ----
    f32x4 gacc[4];
    if (w == 15) {
      if (t > 0) {
        float bv = biasLds[B_OUT2];
        f32x4 oa0 = {bv,bv,bv,bv};
        bf16x8 as[2], bs[2];
        #pragma unroll
        for (int s = 0; s < 2; ++s) { bs[s] = LB(1224 + s); as[s] = LA(OFF_HID,72, rA, s*32+gA*8); }
        #pragma unroll
        for (int s = 0; s < 2; ++s) oa0 = MFMA_B16(as[s], bs[s], oa0);
        if (rA == 0) {
          #pragma unroll
          for (int j = 0; j < 4; ++j)
            __builtin_nontemporal_store(oa0[j], &out[(size_t)(n0 + gA*4 + j)*T_STEPS + (t-1)]);
        }
      }
    } else {
      int blk, tb, nks, hsec, bb, cb;
      if (w < 6)      { blk=w;   tb=1226+w*12;      nks=3; hsec=0;   bb=BG_LIN; cb=0   + w*64; }
      else if (w < 9) { blk=w-6; tb=1298+(w-6)*8;   nks=2; hsec=88;  bb=BG_AC;  cb=384 + (w-6)*64; }
      else            { blk=w-9; tb=1322+(w-9)*12;  nks=3; hsec=136; bb=BG_IM;  cb=576 + (w-9)*64; }
      #pragma unroll
      for (int q = 0; q < 4; ++q) {
        float bv = biasLds[bb + blk*64 + q*16 + rA];
        #pragma unroll
        for (int j = 0; j < 4; ++j) {
          int row = gA*4 + j;
          float xv = b2f(*(const unsigned short*)(lds + OFF_XP + (((size_t)row*968 + cb + q*16 + rA) << 1)));
          gacc[q][j] = bv + xv;
        }
      }
      if (nks == 3) gate_reg_h<3>(gacc, lds, packc, lane, rA, gA, hsec, tb);
      else          gate_reg_h<2>(gacc, lds, packc, lane, rA, gA, hsec, tb);
    }
    __syncthreads();

    // ---- Phase 2: LSTM elementwise ----
    if (w < 15) {
      int blk, hsec, H;
      if (w < 6)      { blk=w;   hsec=0;   H=88; }
      else if (w < 9) { blk=w-6; hsec=88;  H=48; }
      else            { blk=w-9; hsec=136; H=88; }
      int unit = blk*16 + rA;
      if (unit < H) {
        #pragma unroll
        for (int j = 0; j < 4; ++j) {
          float iv = sigm (gacc[0][j]);
          float fv = sigm (gacc[1][j]);
          float gv = tanh_(gacc[2][j]);
          float ov = sigm (gacc[3][j]);
          float cp = cst[j];
          float cn = fv*cp + iv*gv;
          float hn = ov*tanh_(cn);
          cst[j] = cn;
          int row = gA*4 + j;
          STB(OFF_CSTAR,456, row, hsec + unit,        cp);
          STB(OFF_CSTAR,456, row, 224 + hsec + unit,  cn);
          STB(OFF_FEATS,360, row, hsec + unit,        hn);
        }
      }
    }
    __syncthreads();

    // ---- Phase 3: att1 layer1 ----
    if (w < 8) {
      int n = w;
      float bv = biasLds[B_A1H + n*16 + rA];
      f32x4 a0v = {bv,bv,bv,bv};
      bf16x8 a = LA(OFF_CSTAR,456, rA, gA*8);
      reg_loop<14>(packc, lane,
        [&](int i){ return 492 + n*14 + i; },
        [&](int i, bf16x8 bv8){
          a0v = MFMA_B16(a, bv8, a0v);
          if (i + 1 < 14) a = LA(OFF_CSTAR,456, rA, (i+1)*32+gA*8);
        });
      #pragma unroll
      for (int j = 0; j < 4; ++j)
        STB(OFF_HID,136, gA*4 + j, n*16 + rA, fmaxf(a0v[j], 0.f));
    }
    __syncthreads();

    // ---- Phase 4: att1 layer2 -> logits ----
    {
      float bv1 = biasLds[B_LOG + w*16 + rA];
      if (w < 12) {
        float bv2 = biasLds[B_LOG + (w+16)*16 + rA];
        f32x4 l0 = {bv1,bv1,bv1,bv1}, l1 = {bv2,bv2,bv2,bv2};
        bf16x8 a = LA(OFF_HID,136, rA, gA*8);
        reg_loop<8>(packc, lane,
          [&](int i){ int tau = (i < 4) ? w : (w + 16); return 604 + tau*4 + (i & 3); },
          [&](int i, bf16x8 bv8){
            if (i < 4) l0 = MFMA_B16(a, bv8, l0); else l1 = MFMA_B16(a, bv8, l1);
            if (i + 1 < 8) a = LA(OFF_HID,136, rA, ((i+1)&3)*32+gA*8);
          });
        #pragma unroll
        for (int j = 0; j < 4; ++j) {
          STB(OFF_ATT,456, gA*4 + j, w*16 + rA,      l0[j]);
          STB(OFF_ATT,456, gA*4 + j, (w+16)*16 + rA, l1[j]);
        }
      } else {
        f32x4 l0 = {bv1,bv1,bv1,bv1};
        bf16x8 a = LA(OFF_HID,136, rA, gA*8);
        reg_loop<4>(packc, lane,
          [&](int i){ return 604 + w*4 + i; },
          [&](int i, bf16x8 bv8){
            l0 = MFMA_B16(a, bv8, l0);
            if (i + 1 < 4) a = LA(OFF_HID,136, rA, (i+1)*32+gA*8);
          });
        #pragma unroll
        for (int j = 0; j < 4; ++j)
          STB(OFF_ATT,456, gA*4 + j, w*16 + rA, l0[j]);
      }
    }
    __syncthreads();

    // ---- Phase 5: softmax*c_star (w<8) ; nt XP stage for t+1 (w>=8) ----
    if (w < 8) {
      int row = w*2 + (lane >> 5);
      int cb  = lane & 31;
      float v[14];
      float mx = -3.0e38f;
      #pragma unroll
      for (int q = 0; q < 14; ++q) { v[q] = LDB(OFF_ATT,456,row, cb + 32*q); mx = fmaxf(mx, v[q]); }
      #pragma unroll
      for (int mk = 1; mk < 32; mk <<= 1) mx = fmaxf(mx, __shfl_xor(mx, mk));
      float sm = 0.f;
      #pragma unroll
      for (int q = 0; q < 14; ++q) { v[q] = __expf(v[q] - mx); sm += v[q]; }
      #pragma unroll
      for (int mk = 1; mk < 32; mk <<= 1) sm += __shfl_xor(sm, mk);
      float inv = 1.0f / sm;
      #pragma unroll
      for (int q = 0; q < 14; ++q) {
        int c = cb + 32*q;
        float cs = LDB(OFF_CSTAR,456,row,c);
        STB(OFF_ATT,456,row,c, v[q]*inv*cs);
      }
    } else if (t < T_STEPS-1) {
      stage_xp(lds, xp, t+1, n0, tid - 512, 512);
    }
    __syncthreads();

    // ---- Phase 6: att2 layer1 (w8-15: 4+4 cached, ring 20); g1/g2 (w0-7) ----
    if (w >= 8) {
      int nb = (w - 8)*2;
      float b0 = biasLds[B_A2H + nb*16 + rA];
      float b1 = biasLds[B_A2H + (nb+1)*16 + rA];
      f32x4 A0 = {b0,b0,b0,b0}, A1 = {b1,b1,b1,b1};
      // cached K-slices 0..3 from LDS weight cache
      #pragma unroll
      for (int i = 0; i < 4; ++i) {
        bf16x8 a  = LA(OFF_ATT,456, rA, i*32+gA*8);
        bf16x8 w0 = LW(nb*4 + i);
        bf16x8 w1 = LW((nb+1)*4 + i);
        A0 = MFMA_B16(a, w0, A0);
        A1 = MFMA_B16(a, w1, A1);
      }
      // remaining K-slices 4..13 via global ring
      reg_loop<20>(packc, lane,
        [&](int i){ int rr = (i >= 10) ? 1 : 0; int s = 4 + (rr ? (i - 10) : i); return 716 + (nb+rr)*14 + s; },
        [&](int i, bf16x8 bv8){
          int s = 4 + ((i >= 10) ? (i - 10) : i);
          bf16x8 a = LA(OFF_ATT,456, rA, s*32+gA*8);
          if (i < 10) A0 = MFMA_B16(a, bv8, A0); else A1 = MFMA_B16(a, bv8, A1);
        });
      #pragma unroll
      for (int j = 0; j < 4; ++j) {
        STB(OFF_HID,264, gA*4 + j, nb*16 + rA,     fmaxf(A0[j], 0.f));
        STB(OFF_HID,264, gA*4 + j, (nb+1)*16 + rA, fmaxf(A1[j], 0.f));
      }
    } else {
      int which = w >> 2;
      int n = w & 3;
      int tbq = which ? 1076 : 1004;
      int bb  = which ? B_G2H : B_G1H;
      int oo  = which ? OFF_G2H : OFF_G1H;
      float bv = biasLds[bb + n*16 + rA];
      f32x4 A0 = {bv,bv,bv,bv};
      bf16x8 a = LA(OFF_ATT,456, rA, gA*8);
      reg_loop<18>(packc, lane,
        [&](int i){ return tbq + n*18 + i; },
        [&](int i, bf16x8 bv8){
          A0 = MFMA_B16(a, bv8, A0);
          if (i + 1 < 18) {
            a = (i + 1 < 14) ? LA(OFF_ATT,456, rA, (i+1)*32+gA*8)
                             : LA(OFF_FEATS,360, rA, 224 + (i+1-14)*32 + gA*8);
          }
        });
      #pragma unroll
      for (int j = 0; j < 4; ++j)
        STB(oo,72, gA*4 + j, n*16 + rA, fmaxf(A0[j], 0.f));
    }
    __syncthreads();

    // ---- Phase 7: att2 layer2 + gammas + mem ----
    if (w < 8) {
      int n = w;
      float bc = biasLds[B_CHAT + n*16 + rA];
      float b1 = biasLds[B_GM1  + n*16 + rA];
      float b2 = biasLds[B_GM2  + n*16 + rA];
      f32x4 cc0={bc,bc,bc,bc};
      f32x4 g10={b1,b1,b1,b1};
      f32x4 g20={b2,b2,b2,b2};
      bf16x8 a = LA(OFF_HID,264, rA, gA*8);
      reg_loop<12>(packc, lane,
        [&](int i){
          if (i < 8)  return 940 + n*8 + i;
          if (i < 10) return 1148 + n*2 + (i - 8);
          return 1164 + n*2 + (i - 10);
        },
        [&](int i, bf16x8 bv8){
          if (i < 8)       cc0 = MFMA_B16(a, bv8, cc0);
          else if (i < 10) g10 = MFMA_B16(a, bv8, g10);
          else             g20 = MFMA_B16(a, bv8, g20);
          if (i + 1 < 8)        a = LA(OFF_HID,264, rA, (i+1)*32+gA*8);
          else if (i + 1 == 8)  a = LA(OFF_G1H,72, rA, gA*8);
          else if (i + 1 == 9)  a = LA(OFF_G1H,72, rA, 32+gA*8);
          else if (i + 1 == 10) a = LA(OFF_G2H,72, rA, gA*8);
          else if (i + 1 == 11) a = LA(OFF_G2H,72, rA, 32+gA*8);
        });
      #pragma unroll
      for (int j = 0; j < 4; ++j) {
        float ch = tanh_(cc0[j]), ga = sigm(g10[j]), gb = sigm(g20[j]);
        float mn = ga*mreg[j] + gb*ch;
        mreg[j] = mn;
        STB(OFF_FEATS,360, gA*4 + j, 224 + n*16 + rA, mn);
      }
    }
    __syncthreads();

    // ---- Phase 8: out layer1 ----
    if (w < 4) {
      int n = w;
      float bv = biasLds[B_OUTH + n*16 + rA];
      f32x4 a0v = {bv,bv,bv,bv};
      bf16x8 a = LA(OFF_FEATS,360, rA, gA*8);
      reg_loop<11>(packc, lane,
        [&](int i){ return 1180 + n*11 + i; },
        [&](int i, bf16x8 bv8){
          a0v = MFMA_B16(a, bv8, a0v);
          if (i + 1 < 11) a = LA(OFF_FEATS,360, rA, (i+1)*32+gA*8);
        });
      #pragma unroll
      for (int j = 0; j < 4; ++j)
        STB(OFF_HID,72, gA*4 + j, n*16 + rA, fmaxf(a0v[j], 0.f));
    }
    __syncthreads();
  }

  // ---- Final out2 for t = 127 ----
  if (w == 15) {
    float bv = biasLds[B_OUT2];
    f32x4 oa0 = {bv,bv,bv,bv};
    bf16x8 as[2], bs[2];
    #pragma unroll
    for (int s = 0; s < 2; ++s) { bs[s] = LB(1224 + s); as[s] = LA(OFF_HID,72, rA, s*32+gA*8); }
    #pragma unroll
    for (int s = 0; s < 2; ++s) oa0 = MFMA_B16(as[s], bs[s], oa0);
    if (rA == 0) {
      #pragma unroll
      for (int j = 0; j < 4; ++j)
        __builtin_nontemporal_store(oa0[j], &out[(size_t)(n0 + gA*4 + j)*T_STEPS + 127]);
    }
  }
}

extern "C" void kernel_launch(void* const* d_in, const int* in_sizes, int n_in,
                              void* d_out, int out_size, void* d_ws, size_t ws_size,
                              hipStream_t stream) {
  (void)in_sizes; (void)n_in; (void)out_size; (void)ws_size;
  PP P;
  for (int i = 0; i < 35; ++i) P.p[i] = (const float*)d_in[i];
  unsigned short* pack = (unsigned short*)d_ws;
  float* bias = (float*)((char*)d_ws + PACK_BYTES);
  unsigned short* xp = (unsigned short*)((char*)d_ws + PACK_BYTES + 16384);

  hipLaunchKernelGGL(pack_kernel, dim3(320), dim3(256), 0, stream, P, pack, bias);
  hipLaunchKernelGGL(xproj_kernel, dim3(2048), dim3(1024), 0, stream,
                     P.p[0], P.p[1], P.p[2], pack, xp);
  hipLaunchKernelGGL(fused_kernel, dim3(128), dim3(1024), 0, stream,
                     pack, bias, xp, (float*)d_out);
}